// Round 5
// baseline (454.768 us; speedup 1.0000x reference)
//
#include <hip/hip_runtime.h>
#include <hip/hip_bf16.h>
#include <stdint.h>

// Rs_GCN fused pipeline, MI355X (gfx950).
// Algebra: y = (theta phi^T /N) g  ==  theta @ (phi^T g)/N  (no softmax -> associativity).
// W_y = theta @ P, P = (phi^T g) W_w^T / N.  W_b is a per-channel constant under BatchNorm
// (batch-independent) -> dropped (exact). theta/phi/g biases kept.
// I/O dtype: fp32 (per reference). Compute: bf16 MFMA with fp32 accumulation.
// R5 == R4 resubmitted (R4 bench was an infra failure: "container failed twice").
// R4: (1) REVERT R3's LDS swizzle (conflicts->0 but k_proj 83.7->97.9us: conflicts are
// hidden under the vmcnt-drain in this 2-barrier structure, and the source-side chunk
// permutation degraded gld16 coalescing -> uniform slowdown). (2) k_proj moves to BK=64
// (mfma_loop64): halves barrier/drain count; LDS staged as k-split [2][128][32] so each
// subtile keeps the proven 64B-row bank layout; split done by permuting per-lane GLOBAL
// source addresses (LDS dest stays linear). Keep R3's atomic-free k_affin + k_mconv reduce.
// 7 kernels + 1 memset.

using bf16 = __hip_bfloat16;
typedef __attribute__((ext_vector_type(8))) short short8;
typedef __attribute__((ext_vector_type(4))) float f32x4;
typedef __attribute__((ext_vector_type(4))) short short4v;

#define DEVI static __device__ __forceinline__

DEVI float bf2f(unsigned short u) {
  union { unsigned int i; float f; } x; x.i = ((unsigned int)u) << 16; return x.f;
}
DEVI unsigned short f2bf(float f) {
  __hip_bfloat16 h = __float2bfloat16(f);
  return *reinterpret_cast<unsigned short*>(&h);
}

DEVI void gld16(const void* g, void* l) {
  __builtin_amdgcn_global_load_lds((__attribute__((address_space(1))) void*)g,
                                   (__attribute__((address_space(3))) void*)l,
                                   16, 0, 0);
}

DEVI short8 cvt8(float4 a, float4 b) {
  short8 o;
  o[0] = (short)f2bf(a.x); o[1] = (short)f2bf(a.y);
  o[2] = (short)f2bf(a.z); o[3] = (short)f2bf(a.w);
  o[4] = (short)f2bf(b.x); o[5] = (short)f2bf(b.y);
  o[6] = (short)f2bf(b.z); o[7] = (short)f2bf(b.w);
  return o;
}

// C[m][n] += sum_k A[m][k]*B[n][k]; A,B bf16 row-major (K contiguous), 128 rows each,
// K = kiters*32. 256 threads = 4 waves in 2x2; each wave 64x64 via 4x4 MFMA subtiles.
DEVI void mfma_loop(const bf16* A, int ldA, const bf16* B, int ldB,
                    int kiters, bf16* lds_a, bf16* lds_b, f32x4 acc[4][4])
{
  const int tid = threadIdx.x;
  const int lane = tid & 63;
  const int w = tid >> 6;
  const int wr = w >> 1, wc = w & 1;
  const int srow = w * 32 + (lane >> 2);
  const int scol = (lane & 3) * 8;
  const bf16* ga0 = A + (size_t)srow * ldA + scol;
  const bf16* ga1 = A + (size_t)(srow + 16) * ldA + scol;
  const bf16* gb0 = B + (size_t)srow * ldB + scol;
  const bf16* gb1 = B + (size_t)(srow + 16) * ldB + scol;
  bf16* la0 = lds_a + w * 1024 + lane * 8;   // wave-uniform base + lane*16B (contiguous)
  bf16* la1 = la0 + 512;
  bf16* lb0 = lds_b + w * 1024 + lane * 8;
  bf16* lb1 = lb0 + 512;
  const int frow = lane & 15;
  const int fk = (lane >> 4) * 8;
  const bf16* ra = lds_a + (wr * 64 + frow) * 32 + fk;
  const bf16* rb = lds_b + (wc * 64 + frow) * 32 + fk;
  for (int it = 0; it < kiters; ++it) {
    gld16(ga0, la0); gld16(ga1, la1);
    gld16(gb0, lb0); gld16(gb1, lb1);
    ga0 += 32; ga1 += 32; gb0 += 32; gb1 += 32;
    __syncthreads();               // compiler emits vmcnt(0) drain before barrier
    short8 af[4], bfr[4];
#pragma unroll
    for (int i = 0; i < 4; ++i) af[i] = *(const short8*)(ra + i * 512);
#pragma unroll
    for (int j = 0; j < 4; ++j) bfr[j] = *(const short8*)(rb + j * 512);
#pragma unroll
    for (int i = 0; i < 4; ++i)
#pragma unroll
      for (int j = 0; j < 4; ++j)
        acc[i][j] = __builtin_amdgcn_mfma_f32_16x16x32_bf16(af[i], bfr[j], acc[i][j], 0, 0, 0);
    __syncthreads();
  }
}

// BK=64 variant: K = kiters64*64. LDS is k-split [2][128][32] per operand (16KB each):
// subtile kk holds k-elements kk*32..kk*32+31 for all 128 rows, in the SAME 64B-row
// layout as mfma_loop (bank behavior unchanged). The split is achieved by permuting the
// per-lane GLOBAL source address; the gld16 LDS destination stays linear (rule #21).
// Halves the barrier/vmcnt-drain count vs BK32.
DEVI void mfma_loop64(const bf16* A, int ldA, const bf16* B, int ldB,
                      int kiters64, bf16* lds_a, bf16* lds_b, f32x4 acc[4][4])
{
  const int tid = threadIdx.x;
  const int lane = tid & 63;
  const int w = tid >> 6;
  const int wr = w >> 1, wc = w & 1;
  // Staging: 1024 16B-chunks per operand per iter, 4 gld16/thread.
  // LDS chunk index p = s*256 + tid maps to [ksub][row][c2]: ksub=p>>9, row=(p>>2)&127,
  // c2=p&3. Global source element = row*ld + ksub*32 + c2*8.
  const bf16* gA[4]; const bf16* gB[4]; bf16* dA[4]; bf16* dB[4];
#pragma unroll
  for (int s = 0; s < 4; ++s) {
    const int p = s * 256 + tid;
    const int ksub = p >> 9;
    const int row = (p >> 2) & 127;
    const int c2 = p & 3;
    gA[s] = A + (size_t)row * ldA + ksub * 32 + c2 * 8;
    gB[s] = B + (size_t)row * ldB + ksub * 32 + c2 * 8;
    dA[s] = lds_a + s * 2048 + w * 512 + lane * 8;   // linear: chunk p at byte p*16
    dB[s] = lds_b + s * 2048 + w * 512 + lane * 8;
  }
  const int frow = lane & 15;
  const int fk = (lane >> 4) * 8;
  const bf16* ra = lds_a + (wr * 64 + frow) * 32 + fk;
  const bf16* rb = lds_b + (wc * 64 + frow) * 32 + fk;
  for (int it = 0; it < kiters64; ++it) {
#pragma unroll
    for (int s = 0; s < 4; ++s) gld16(gA[s], dA[s]);
#pragma unroll
    for (int s = 0; s < 4; ++s) gld16(gB[s], dB[s]);
#pragma unroll
    for (int s = 0; s < 4; ++s) { gA[s] += 64; gB[s] += 64; }
    __syncthreads();
#pragma unroll
    for (int kk = 0; kk < 2; ++kk) {
      short8 af[4], bfr[4];
#pragma unroll
      for (int i = 0; i < 4; ++i) af[i] = *(const short8*)(ra + kk * 4096 + i * 512);
#pragma unroll
      for (int j = 0; j < 4; ++j) bfr[j] = *(const short8*)(rb + kk * 4096 + j * 512);
#pragma unroll
      for (int i = 0; i < 4; ++i)
#pragma unroll
        for (int j = 0; j < 4; ++j)
          acc[i][j] = __builtin_amdgcn_mfma_f32_16x16x32_bf16(af[i], bfr[j], acc[i][j], 0, 0, 0);
    }
    __syncthreads();
  }
}

#define ACC_INIT(acc)                                   \
  _Pragma("unroll") for (int i = 0; i < 4; ++i)         \
  _Pragma("unroll") for (int j = 0; j < 4; ++j)         \
      acc[i][j] = (f32x4){0.f, 0.f, 0.f, 0.f};

// ---- All fp32->bf16 casts in ONE launch: v (16384 blocks) + 4 weights (128 each). ----
__global__ __launch_bounds__(256) void k_cast_all(
    const float* __restrict__ v, bf16* __restrict__ vbf,
    const float* __restrict__ s0, const float* __restrict__ s1,
    const float* __restrict__ s2, const float* __restrict__ s3,
    bf16* __restrict__ d0, bf16* __restrict__ d1,
    bf16* __restrict__ d2, bf16* __restrict__ d3)
{
  const float* in; bf16* out; size_t base;
  const int bx = blockIdx.x;
  if (bx < 16384) {
    in = v; out = vbf; base = (size_t)bx * 2048;
  } else {
    const int wq = bx - 16384;
    switch (wq >> 7) {
      case 0:  in = s0; out = d0; break;
      case 1:  in = s1; out = d1; break;
      case 2:  in = s2; out = d2; break;
      default: in = s3; out = d3; break;
    }
    base = (size_t)(wq & 127) * 2048;
  }
  const size_t idx = base + (size_t)threadIdx.x * 8;
  float4 a = *(const float4*)(in + idx);
  float4 b = *(const float4*)(in + idx + 4);
  *(short8*)(out + idx) = cvt8(a, b);
}

// ---- Kernel A: projections. theta token-major; phi,g transposed [b][ic][n]. ----
__global__ __launch_bounds__(256) void k_proj(
    const bf16* __restrict__ vbf,
    const bf16* __restrict__ w_th, const float* __restrict__ b_th,
    const bf16* __restrict__ w_ph, const float* __restrict__ b_ph,
    const bf16* __restrict__ w_g,  const float* __restrict__ b_g,
    bf16* __restrict__ theta, bf16* __restrict__ phiT, bf16* __restrict__ gT)
{
  __shared__ __align__(16) char smem[34048];   // staging 2x16KB (BK64); epilogue 128x133 bf16
  bf16* lds_a = (bf16*)smem;
  bf16* lds_b = (bf16*)(smem + 16384);
  unsigned short* lds_t = (unsigned short*)smem;

  const int tt = blockIdx.x;        // token tile 0..255
  const int yy = blockIdx.y;        // 0..5
  const int proj = yy >> 1;         // 0 theta, 1 phi, 2 g
  const int icb = (yy & 1) * 128;
  const bf16* wsel = (proj == 0) ? w_th : ((proj == 1) ? w_ph : w_g);
  const float* bsel = (proj == 0) ? b_th : ((proj == 1) ? b_ph : b_g);

  const size_t t0 = (size_t)tt * 128;
  f32x4 acc[4][4];
  ACC_INIT(acc);
  mfma_loop64(vbf + t0 * 1024, 1024, wsel + (size_t)icb * 1024, 1024, 16, lds_a, lds_b, acc);

  const int tid = threadIdx.x, lane = tid & 63, w = tid >> 6;
  const int wr = w >> 1, wc = w & 1, quad = lane >> 4, l15 = lane & 15;
  float biasv[4];
#pragma unroll
  for (int j = 0; j < 4; ++j) biasv[j] = bsel[icb + wc * 64 + j * 16 + l15];

  if (proj == 0) {
#pragma unroll
    for (int i = 0; i < 4; ++i)
#pragma unroll
      for (int j = 0; j < 4; ++j)
#pragma unroll
        for (int r = 0; r < 4; ++r) {
          int m = wr * 64 + i * 16 + quad * 4 + r;
          int n = wc * 64 + j * 16 + l15;
          theta[(t0 + m) * 256 + icb + n] = __float2bfloat16(acc[i][j][r] + biasv[j]);
        }
  } else {
#pragma unroll
    for (int i = 0; i < 4; ++i)
#pragma unroll
      for (int j = 0; j < 4; ++j)
#pragma unroll
        for (int r = 0; r < 4; ++r) {
          int m = wr * 64 + i * 16 + quad * 4 + r;
          int n = wc * 64 + j * 16 + l15;
          lds_t[m * 133 + n] = f2bf(acc[i][j][r] + biasv[j]);
        }
    __syncthreads();
    bf16* outT = (proj == 1) ? phiT : gT;
    const int bb = (int)(t0 >> 12);
    const int n0 = (int)(t0 & 4095);
    const int tg = tid & 7;        // token group (coalesces stores across lanes)
    const int ch0 = tid >> 3;      // 0..31
#pragma unroll
    for (int half = 0; half < 2; ++half)
#pragma unroll
      for (int cc = 0; cc < 4; ++cc) {
        int ch = ch0 + cc * 32;
        int tok0 = half * 64 + tg * 8;
        short8 pk;
#pragma unroll
        for (int r = 0; r < 8; ++r) pk[r] = (short)lds_t[(tok0 + r) * 133 + ch];
        *(short8*)(outT + ((size_t)(bb * 256 + icb + ch)) * 4096 + n0 + tok0) = pk;
      }
  }
}

// ---- Kernel B: Mp[kc][b] = phi[kc-chunk]^T g[kc-chunk], plain stores (atomic-free). ----
__global__ __launch_bounds__(256) void k_affin(
    const bf16* __restrict__ phiT, const bf16* __restrict__ gT, float* __restrict__ Mp)
{
  __shared__ __align__(16) char smem[16384];
  bf16* lds_a = (bf16*)smem;
  bf16* lds_b = (bf16*)(smem + 8192);
  const int kc = blockIdx.x;        // 0..7 K-chunk
  const int jt = blockIdx.y >> 1;   // 0..1
  const int it2 = blockIdx.y & 1;   // 0..1
  const int bb = blockIdx.z;        // 0..7
  f32x4 acc[4][4];
  ACC_INIT(acc);
  const bf16* A = phiT + ((size_t)bb * 256 + jt * 128) * 4096 + kc * 512;
  const bf16* B = gT   + ((size_t)bb * 256 + it2 * 128) * 4096 + kc * 512;
  mfma_loop(A, 4096, B, 4096, 16, lds_a, lds_b, acc);
  const int tid = threadIdx.x, lane = tid & 63, w = tid >> 6;
  const int wr = w >> 1, wc = w & 1, quad = lane >> 4, l15 = lane & 15;
  float* Mb = Mp + ((size_t)kc * 8 + bb) * 65536;
#pragma unroll
  for (int i = 0; i < 4; ++i)
#pragma unroll
    for (int j = 0; j < 4; ++j)
#pragma unroll
      for (int r = 0; r < 4; ++r) {
        int m = wr * 64 + i * 16 + quad * 4 + r;
        int n = wc * 64 + j * 16 + l15;
        Mb[(size_t)(jt * 128 + m) * 256 + it2 * 128 + n] = acc[i][j][r];
      }
}

// ---- Reduce 8 kc-partials -> bf16, folding the 1/N affinity normalization. ----
__global__ __launch_bounds__(256) void k_mconv(const float* __restrict__ Mp, bf16* __restrict__ Mbf)
{
  const size_t i = ((size_t)blockIdx.x * 256 + threadIdx.x) * 4;   // 524288 elems / 4
  float4 s = *(const float4*)(Mp + i);
#pragma unroll
  for (int kc = 1; kc < 8; ++kc) {
    float4 p = *(const float4*)(Mp + (size_t)kc * 524288 + i);
    s.x += p.x; s.y += p.y; s.z += p.z; s.w += p.w;
  }
  short4v o;
  o[0] = (short)f2bf(s.x * (1.0f / 4096.0f));
  o[1] = (short)f2bf(s.y * (1.0f / 4096.0f));
  o[2] = (short)f2bf(s.z * (1.0f / 4096.0f));
  o[3] = (short)f2bf(s.w * (1.0f / 4096.0f));
  *(short4v*)(Mbf + i) = o;
}

// ---- Kernel C: PT[b][c][j] = sum_i W_w[c][i] * Mbf[b][j][i]. ----
__global__ __launch_bounds__(256) void k_pt(
    const bf16* __restrict__ Ww, const bf16* __restrict__ Mbf, bf16* __restrict__ PT)
{
  __shared__ __align__(16) char smem[16384];
  bf16* lds_a = (bf16*)smem;
  bf16* lds_b = (bf16*)(smem + 8192);
  const int ct = blockIdx.x;   // 0..7
  const int jt = blockIdx.y;   // 0..1
  const int bb = blockIdx.z;   // 0..7
  f32x4 acc[4][4];
  ACC_INIT(acc);
  mfma_loop(Ww + (size_t)ct * 128 * 256, 256,
            Mbf + ((size_t)bb * 256 + jt * 128) * 256, 256, 8, lds_a, lds_b, acc);
  const int tid = threadIdx.x, lane = tid & 63, w = tid >> 6;
  const int wr = w >> 1, wc = w & 1, quad = lane >> 4, l15 = lane & 15;
#pragma unroll
  for (int i = 0; i < 4; ++i)
#pragma unroll
    for (int j = 0; j < 4; ++j)
#pragma unroll
      for (int r = 0; r < 4; ++r) {
        int m = wr * 64 + i * 16 + quad * 4 + r;
        int n = wc * 64 + j * 16 + l15;
        PT[((size_t)bb * 1024 + ct * 128 + m) * 256 + jt * 128 + n] = __float2bfloat16(acc[i][j][r]);
      }
}

// ---- Kernel D: Wy[t][c] = sum_j theta[t][j] * PT[b][c][j]. BN stats fused (fp32 acc). ----
__global__ __launch_bounds__(256) void k_wy(
    const bf16* __restrict__ theta, const bf16* __restrict__ PT, bf16* __restrict__ Wy,
    float* __restrict__ sums, float* __restrict__ sumsq)
{
  __shared__ __align__(16) char smem[16384];
  bf16* lds_a = (bf16*)smem;
  bf16* lds_b = (bf16*)(smem + 8192);
  const size_t t0 = (size_t)blockIdx.x * 128;
  const int ct = blockIdx.y;           // 0..7
  const int bb = (int)(t0 >> 12);
  f32x4 acc[4][4];
  ACC_INIT(acc);
  mfma_loop(theta + t0 * 256, 256,
            PT + ((size_t)bb * 1024 + ct * 128) * 256, 256, 8, lds_a, lds_b, acc);
  const int tid = threadIdx.x, lane = tid & 63, w = tid >> 6;
  const int wr = w >> 1, wc = w & 1, quad = lane >> 4, l15 = lane & 15;
  float ps[4] = {0.f, 0.f, 0.f, 0.f}, pq[4] = {0.f, 0.f, 0.f, 0.f};
#pragma unroll
  for (int i = 0; i < 4; ++i)
#pragma unroll
    for (int j = 0; j < 4; ++j)
#pragma unroll
      for (int r = 0; r < 4; ++r) {
        int m = wr * 64 + i * 16 + quad * 4 + r;
        int n = wc * 64 + j * 16 + l15;
        float f = acc[i][j][r];
        Wy[(t0 + m) * 1024 + ct * 128 + n] = __float2bfloat16(f);
        ps[j] += f; pq[j] += f * f;
      }
  // quad-reduce: lanes {l15, l15+16, l15+32, l15+48} hold partials for the same channel
#pragma unroll
  for (int j = 0; j < 4; ++j) {
    ps[j] += __shfl_xor(ps[j], 16); ps[j] += __shfl_xor(ps[j], 32);
    pq[j] += __shfl_xor(pq[j], 16); pq[j] += __shfl_xor(pq[j], 32);
  }
  if (quad == 0) {
#pragma unroll
    for (int j = 0; j < 4; ++j) {
      int c = ct * 128 + wc * 64 + j * 16 + l15;
      atomicAdd(&sums[c], ps[j]);
      atomicAdd(&sumsq[c], pq[j]);
    }
  }
}

// ---- Output: BN affine computed inline from sums/sumsq (k_norm folded in). ----
// out = Wy*scale + shift + v, 4 elems/thread. sums/sumsq/gamma/beta are L2-hot.
__global__ __launch_bounds__(256) void k_out(const bf16* __restrict__ Wy, const float* __restrict__ v,
                                             const float* __restrict__ sums, const float* __restrict__ sumsq,
                                             const float* __restrict__ gamma, const float* __restrict__ beta,
                                             float* __restrict__ out)
{
  const size_t idx = ((size_t)blockIdx.x * 256 + threadIdx.x) * 4;
  const int c = (int)(idx & 1023);
  float4 sm = *(const float4*)(sums + c);
  float4 sq = *(const float4*)(sumsq + c);
  float4 gm = *(const float4*)(gamma + c);
  float4 bt = *(const float4*)(beta + c);
  short4v wv = *(const short4v*)(Wy + idx);
  float4 vv = *(const float4*)(v + idx);
  float4 o;
#pragma unroll
  for (int k = 0; k < 4; ++k) {
    float smk = (&sm.x)[k], sqk = (&sq.x)[k], gmk = (&gm.x)[k], btk = (&bt.x)[k];
    float mean = smk * (1.0f / 32768.0f);
    float var = sqk * (1.0f / 32768.0f) - mean * mean;
    float sc = gmk * rsqrtf(var + 1e-5f);
    float sh = btk - mean * sc;
    (&o.x)[k] = bf2f((unsigned short)wv[k]) * sc + sh + (&vv.x)[k];
  }
  *(float4*)(out + idx) = o;
}

extern "C" void kernel_launch(void* const* d_in, const int* in_sizes, int n_in,
                              void* d_out, int out_size, void* d_ws, size_t ws_size,
                              hipStream_t stream)
{
  (void)in_sizes; (void)n_in; (void)out_size; (void)ws_size;
  const float* v    = (const float*)d_in[0];
  const float* g_w  = (const float*)d_in[1];
  const float* g_b  = (const float*)d_in[2];
  const float* th_w = (const float*)d_in[3];
  const float* th_b = (const float*)d_in[4];
  const float* ph_w = (const float*)d_in[5];
  const float* ph_b = (const float*)d_in[6];
  const float* W_w  = (const float*)d_in[7];
  // d_in[8] = W_b: per-channel constant, exactly cancelled by BatchNorm mean. Unused.
  const float* gamma = (const float*)d_in[9];
  const float* beta  = (const float*)d_in[10];
  float* out = (float*)d_out;

  char* ws = (char*)d_ws;
  bf16* vbf  = (bf16*)ws;              // 64 MiB; dead after k_proj
  bf16* Wy   = (bf16*)ws;              // aliases vbf (written by k_wy, after k_mconv reads Mp)
  float* Mp  = (float*)ws;             // 16 MiB kc-partials; aliases dead vbf (k_affin..k_mconv)
  ws += (size_t)32768 * 1024 * 2;
  bf16* theta = (bf16*)ws;  ws += (size_t)32768 * 256 * 2;    // 16 MiB
  bf16* phiT  = (bf16*)ws;  ws += (size_t)32768 * 256 * 2;    // 16 MiB
  bf16* gT    = (bf16*)ws;  ws += (size_t)32768 * 256 * 2;    // 16 MiB
  bf16* Mbf   = (bf16*)ws;  ws += (size_t)8 * 65536 * 2;      // 1 MiB
  bf16* PT    = (bf16*)ws;  ws += (size_t)8 * 1024 * 256 * 2; // 4 MiB
  bf16* thwb  = (bf16*)ws;  ws += (size_t)256 * 1024 * 2;
  bf16* phwb  = (bf16*)ws;  ws += (size_t)256 * 1024 * 2;
  bf16* gwb   = (bf16*)ws;  ws += (size_t)256 * 1024 * 2;
  bf16* Wwb   = (bf16*)ws;  ws += (size_t)1024 * 256 * 2;
  float* sums = (float*)ws; ws += 4096;
  float* sumsq= (float*)ws; ws += 4096;

  hipMemsetAsync(sums, 0, 8192, stream);   // sums + sumsq (contiguous)

  k_cast_all<<<16384 + 512, 256, 0, stream>>>(v, vbf, th_w, ph_w, g_w, W_w,
                                              thwb, phwb, gwb, Wwb);

  k_proj <<<dim3(256, 6), 256, 0, stream>>>(vbf, thwb, th_b, phwb, ph_b, gwb, g_b, theta, phiT, gT);
  k_affin<<<dim3(8, 4, 8), 256, 0, stream>>>(phiT, gT, Mp);
  k_mconv<<<512, 256, 0, stream>>>(Mp, Mbf);
  k_pt   <<<dim3(8, 2, 8), 256, 0, stream>>>(Wwb, Mbf, PT);
  k_wy   <<<dim3(256, 8), 256, 0, stream>>>(theta, PT, Wy, sums, sumsq);
  k_out  <<<32768, 256, 0, stream>>>(Wy, v, sums, sumsq, gamma, beta, out);
}

// Round 6
// 450.969 us; speedup vs baseline: 1.0084x; 1.0084x over previous
//
#include <hip/hip_runtime.h>
#include <hip/hip_bf16.h>
#include <stdint.h>

// Rs_GCN fused pipeline, MI355X (gfx950).
// Algebra: y = (theta phi^T /N) g  ==  theta @ (phi^T g)/N  (no softmax -> associativity).
// W_y = theta @ P, P = (phi^T g) W_w^T / N.  W_b is a per-channel constant under BatchNorm
// (batch-independent) -> dropped (exact). theta/phi/g biases kept.
// I/O dtype: fp32 (per reference). Compute: bf16 MFMA with fp32 accumulation.
// R6: (1) Reinstate R3's both-sides LDS swizzle in mfma_loop (k_affin/k_pt/k_wy only):
// R3->R5 accounting shows conflict-free ds_read was worth ~23us in those kernels (short
// K-loops / low occupancy put LDS reads on the critical path), while k_proj paid the
// source-permutation cost -- so k_proj keeps the UNswizzled BK64 loop (mfma_loop64, R5:
// dropped out of top-5, <78us). (2) sums/sumsq zeroing folded into k_cast_all (memset
// dispatch dropped). 7 kernels, 0 memsets. The 512MiB/78us fillBufferAligned in top-5 is
// the harness workspace re-poison at 86% HBM peak -- untouchable floor.

using bf16 = __hip_bfloat16;
typedef __attribute__((ext_vector_type(8))) short short8;
typedef __attribute__((ext_vector_type(4))) float f32x4;
typedef __attribute__((ext_vector_type(4))) short short4v;

#define DEVI static __device__ __forceinline__

DEVI float bf2f(unsigned short u) {
  union { unsigned int i; float f; } x; x.i = ((unsigned int)u) << 16; return x.f;
}
DEVI unsigned short f2bf(float f) {
  __hip_bfloat16 h = __float2bfloat16(f);
  return *reinterpret_cast<unsigned short*>(&h);
}

DEVI void gld16(const void* g, void* l) {
  __builtin_amdgcn_global_load_lds((__attribute__((address_space(1))) void*)g,
                                   (__attribute__((address_space(3))) void*)l,
                                   16, 0, 0);
}

DEVI short8 cvt8(float4 a, float4 b) {
  short8 o;
  o[0] = (short)f2bf(a.x); o[1] = (short)f2bf(a.y);
  o[2] = (short)f2bf(a.z); o[3] = (short)f2bf(a.w);
  o[4] = (short)f2bf(b.x); o[5] = (short)f2bf(b.y);
  o[6] = (short)f2bf(b.z); o[7] = (short)f2bf(b.w);
  return o;
}

// C[m][n] += sum_k A[m][k]*B[n][k]; A,B bf16 row-major (K contiguous), 128 rows each,
// K = kiters*32. 256 threads = 4 waves in 2x2; each wave 64x64 via 4x4 MFMA subtiles.
// LDS tiles [128][32] with col-block XOR swizzle: physical colblk = logical ^ ((row>>1)&3).
// Writer side applied by permuting the GLOBAL source 16B-chunk per lane (gld16 dest linear,
// rule #21); reader applies the same XOR. Conflicts on ds_read_b128: 8-way -> 0 (measured
// R3). Used by k_affin/k_pt/k_wy (short K-loops: LDS reads on critical path). NOT by
// k_proj (R3: source permutation cost it +14us; it uses mfma_loop64).
DEVI void mfma_loop(const bf16* A, int ldA, const bf16* B, int ldB,
                    int kiters, bf16* lds_a, bf16* lds_b, f32x4 acc[4][4])
{
  const int tid = threadIdx.x;
  const int lane = tid & 63;
  const int w = tid >> 6;
  const int wr = w >> 1, wc = w & 1;
  const int srow = w * 32 + (lane >> 2);
  const int scol = (((lane & 3) ^ ((srow >> 1) & 3))) * 8;   // source-side swizzle
  const bf16* ga0 = A + (size_t)srow * ldA + scol;
  const bf16* ga1 = A + (size_t)(srow + 16) * ldA + scol;    // (srow+16)>>1 & 3 == srow>>1 & 3
  const bf16* gb0 = B + (size_t)srow * ldB + scol;
  const bf16* gb1 = B + (size_t)(srow + 16) * ldB + scol;
  bf16* la0 = lds_a + w * 1024 + lane * 8;   // wave-uniform base + lane*16B (contiguous)
  bf16* la1 = la0 + 512;
  bf16* lb0 = lds_b + w * 1024 + lane * 8;
  bf16* lb1 = lb0 + 512;
  const int frow = lane & 15;
  const int fk = (((lane >> 4) ^ ((frow >> 1) & 3))) * 8;    // read-side swizzle (same XOR)
  const bf16* ra = lds_a + (wr * 64 + frow) * 32 + fk;
  const bf16* rb = lds_b + (wc * 64 + frow) * 32 + fk;
  for (int it = 0; it < kiters; ++it) {
    gld16(ga0, la0); gld16(ga1, la1);
    gld16(gb0, lb0); gld16(gb1, lb1);
    ga0 += 32; ga1 += 32; gb0 += 32; gb1 += 32;
    __syncthreads();               // compiler emits vmcnt(0) drain before barrier
    short8 af[4], bfr[4];
#pragma unroll
    for (int i = 0; i < 4; ++i) af[i] = *(const short8*)(ra + i * 512);   // +16 rows: swz invariant
#pragma unroll
    for (int j = 0; j < 4; ++j) bfr[j] = *(const short8*)(rb + j * 512);
#pragma unroll
    for (int i = 0; i < 4; ++i)
#pragma unroll
      for (int j = 0; j < 4; ++j)
        acc[i][j] = __builtin_amdgcn_mfma_f32_16x16x32_bf16(af[i], bfr[j], acc[i][j], 0, 0, 0);
    __syncthreads();
  }
}

// BK=64 variant: K = kiters64*64. LDS is k-split [2][128][32] per operand (16KB each):
// subtile kk holds k-elements kk*32..kk*32+31 for all 128 rows, in the SAME 64B-row
// layout as the BK32 loop (bank behavior unchanged). Split achieved by permuting the
// per-lane GLOBAL source address; gld16 LDS destination stays linear (rule #21).
// Halves the barrier/vmcnt-drain count vs BK32. Unswizzled (R3 evidence: k_proj slower
// with swizzle).
DEVI void mfma_loop64(const bf16* A, int ldA, const bf16* B, int ldB,
                      int kiters64, bf16* lds_a, bf16* lds_b, f32x4 acc[4][4])
{
  const int tid = threadIdx.x;
  const int lane = tid & 63;
  const int w = tid >> 6;
  const int wr = w >> 1, wc = w & 1;
  const bf16* gA[4]; const bf16* gB[4]; bf16* dA[4]; bf16* dB[4];
#pragma unroll
  for (int s = 0; s < 4; ++s) {
    const int p = s * 256 + tid;
    const int ksub = p >> 9;
    const int row = (p >> 2) & 127;
    const int c2 = p & 3;
    gA[s] = A + (size_t)row * ldA + ksub * 32 + c2 * 8;
    gB[s] = B + (size_t)row * ldB + ksub * 32 + c2 * 8;
    dA[s] = lds_a + s * 2048 + w * 512 + lane * 8;   // linear: chunk p at byte p*16
    dB[s] = lds_b + s * 2048 + w * 512 + lane * 8;
  }
  const int frow = lane & 15;
  const int fk = (lane >> 4) * 8;
  const bf16* ra = lds_a + (wr * 64 + frow) * 32 + fk;
  const bf16* rb = lds_b + (wc * 64 + frow) * 32 + fk;
  for (int it = 0; it < kiters64; ++it) {
#pragma unroll
    for (int s = 0; s < 4; ++s) gld16(gA[s], dA[s]);
#pragma unroll
    for (int s = 0; s < 4; ++s) gld16(gB[s], dB[s]);
#pragma unroll
    for (int s = 0; s < 4; ++s) { gA[s] += 64; gB[s] += 64; }
    __syncthreads();
#pragma unroll
    for (int kk = 0; kk < 2; ++kk) {
      short8 af[4], bfr[4];
#pragma unroll
      for (int i = 0; i < 4; ++i) af[i] = *(const short8*)(ra + kk * 4096 + i * 512);
#pragma unroll
      for (int j = 0; j < 4; ++j) bfr[j] = *(const short8*)(rb + kk * 4096 + j * 512);
#pragma unroll
      for (int i = 0; i < 4; ++i)
#pragma unroll
        for (int j = 0; j < 4; ++j)
          acc[i][j] = __builtin_amdgcn_mfma_f32_16x16x32_bf16(af[i], bfr[j], acc[i][j], 0, 0, 0);
    }
    __syncthreads();
  }
}

#define ACC_INIT(acc)                                   \
  _Pragma("unroll") for (int i = 0; i < 4; ++i)         \
  _Pragma("unroll") for (int j = 0; j < 4; ++j)         \
      acc[i][j] = (f32x4){0.f, 0.f, 0.f, 0.f};

// ---- All fp32->bf16 casts in ONE launch: v (16384 blocks) + 4 weights (128 each)
// + 1 block zeroing sums/sumsq (replaces the memset dispatch). ----
__global__ __launch_bounds__(256) void k_cast_all(
    const float* __restrict__ v, bf16* __restrict__ vbf,
    const float* __restrict__ s0, const float* __restrict__ s1,
    const float* __restrict__ s2, const float* __restrict__ s3,
    bf16* __restrict__ d0, bf16* __restrict__ d1,
    bf16* __restrict__ d2, bf16* __restrict__ d3,
    float* __restrict__ zbuf)
{
  const int bx = blockIdx.x;
  if (bx == 16384 + 512) {     // zero sums+sumsq: 2048 floats
    float4 z = {0.f, 0.f, 0.f, 0.f};
    *(float4*)(zbuf + threadIdx.x * 8) = z;
    *(float4*)(zbuf + threadIdx.x * 8 + 4) = z;
    return;
  }
  const float* in; bf16* out; size_t base;
  if (bx < 16384) {
    in = v; out = vbf; base = (size_t)bx * 2048;
  } else {
    const int wq = bx - 16384;
    switch (wq >> 7) {
      case 0:  in = s0; out = d0; break;
      case 1:  in = s1; out = d1; break;
      case 2:  in = s2; out = d2; break;
      default: in = s3; out = d3; break;
    }
    base = (size_t)(wq & 127) * 2048;
  }
  const size_t idx = base + (size_t)threadIdx.x * 8;
  float4 a = *(const float4*)(in + idx);
  float4 b = *(const float4*)(in + idx + 4);
  *(short8*)(out + idx) = cvt8(a, b);
}

// ---- Kernel A: projections. theta token-major; phi,g transposed [b][ic][n]. ----
__global__ __launch_bounds__(256) void k_proj(
    const bf16* __restrict__ vbf,
    const bf16* __restrict__ w_th, const float* __restrict__ b_th,
    const bf16* __restrict__ w_ph, const float* __restrict__ b_ph,
    const bf16* __restrict__ w_g,  const float* __restrict__ b_g,
    bf16* __restrict__ theta, bf16* __restrict__ phiT, bf16* __restrict__ gT)
{
  __shared__ __align__(16) char smem[34048];   // staging 2x16KB (BK64); epilogue 128x133 bf16
  bf16* lds_a = (bf16*)smem;
  bf16* lds_b = (bf16*)(smem + 16384);
  unsigned short* lds_t = (unsigned short*)smem;

  const int tt = blockIdx.x;        // token tile 0..255
  const int yy = blockIdx.y;        // 0..5
  const int proj = yy >> 1;         // 0 theta, 1 phi, 2 g
  const int icb = (yy & 1) * 128;
  const bf16* wsel = (proj == 0) ? w_th : ((proj == 1) ? w_ph : w_g);
  const float* bsel = (proj == 0) ? b_th : ((proj == 1) ? b_ph : b_g);

  const size_t t0 = (size_t)tt * 128;
  f32x4 acc[4][4];
  ACC_INIT(acc);
  mfma_loop64(vbf + t0 * 1024, 1024, wsel + (size_t)icb * 1024, 1024, 16, lds_a, lds_b, acc);

  const int tid = threadIdx.x, lane = tid & 63, w = tid >> 6;
  const int wr = w >> 1, wc = w & 1, quad = lane >> 4, l15 = lane & 15;
  float biasv[4];
#pragma unroll
  for (int j = 0; j < 4; ++j) biasv[j] = bsel[icb + wc * 64 + j * 16 + l15];

  if (proj == 0) {
#pragma unroll
    for (int i = 0; i < 4; ++i)
#pragma unroll
      for (int j = 0; j < 4; ++j)
#pragma unroll
        for (int r = 0; r < 4; ++r) {
          int m = wr * 64 + i * 16 + quad * 4 + r;
          int n = wc * 64 + j * 16 + l15;
          theta[(t0 + m) * 256 + icb + n] = __float2bfloat16(acc[i][j][r] + biasv[j]);
        }
  } else {
#pragma unroll
    for (int i = 0; i < 4; ++i)
#pragma unroll
      for (int j = 0; j < 4; ++j)
#pragma unroll
        for (int r = 0; r < 4; ++r) {
          int m = wr * 64 + i * 16 + quad * 4 + r;
          int n = wc * 64 + j * 16 + l15;
          lds_t[m * 133 + n] = f2bf(acc[i][j][r] + biasv[j]);
        }
    __syncthreads();
    bf16* outT = (proj == 1) ? phiT : gT;
    const int bb = (int)(t0 >> 12);
    const int n0 = (int)(t0 & 4095);
    const int tg = tid & 7;        // token group (coalesces stores across lanes)
    const int ch0 = tid >> 3;      // 0..31
#pragma unroll
    for (int half = 0; half < 2; ++half)
#pragma unroll
      for (int cc = 0; cc < 4; ++cc) {
        int ch = ch0 + cc * 32;
        int tok0 = half * 64 + tg * 8;
        short8 pk;
#pragma unroll
        for (int r = 0; r < 8; ++r) pk[r] = (short)lds_t[(tok0 + r) * 133 + ch];
        *(short8*)(outT + ((size_t)(bb * 256 + icb + ch)) * 4096 + n0 + tok0) = pk;
      }
  }
}

// ---- Kernel B: Mp[kc][b] = phi[kc-chunk]^T g[kc-chunk], plain stores (atomic-free). ----
__global__ __launch_bounds__(256) void k_affin(
    const bf16* __restrict__ phiT, const bf16* __restrict__ gT, float* __restrict__ Mp)
{
  __shared__ __align__(16) char smem[16384];
  bf16* lds_a = (bf16*)smem;
  bf16* lds_b = (bf16*)(smem + 8192);
  const int kc = blockIdx.x;        // 0..7 K-chunk
  const int jt = blockIdx.y >> 1;   // 0..1
  const int it2 = blockIdx.y & 1;   // 0..1
  const int bb = blockIdx.z;        // 0..7
  f32x4 acc[4][4];
  ACC_INIT(acc);
  const bf16* A = phiT + ((size_t)bb * 256 + jt * 128) * 4096 + kc * 512;
  const bf16* B = gT   + ((size_t)bb * 256 + it2 * 128) * 4096 + kc * 512;
  mfma_loop(A, 4096, B, 4096, 16, lds_a, lds_b, acc);
  const int tid = threadIdx.x, lane = tid & 63, w = tid >> 6;
  const int wr = w >> 1, wc = w & 1, quad = lane >> 4, l15 = lane & 15;
  float* Mb = Mp + ((size_t)kc * 8 + bb) * 65536;
#pragma unroll
  for (int i = 0; i < 4; ++i)
#pragma unroll
    for (int j = 0; j < 4; ++j)
#pragma unroll
      for (int r = 0; r < 4; ++r) {
        int m = wr * 64 + i * 16 + quad * 4 + r;
        int n = wc * 64 + j * 16 + l15;
        Mb[(size_t)(jt * 128 + m) * 256 + it2 * 128 + n] = acc[i][j][r];
      }
}

// ---- Reduce 8 kc-partials -> bf16, folding the 1/N affinity normalization. ----
__global__ __launch_bounds__(256) void k_mconv(const float* __restrict__ Mp, bf16* __restrict__ Mbf)
{
  const size_t i = ((size_t)blockIdx.x * 256 + threadIdx.x) * 4;   // 524288 elems / 4
  float4 s = *(const float4*)(Mp + i);
#pragma unroll
  for (int kc = 1; kc < 8; ++kc) {
    float4 p = *(const float4*)(Mp + (size_t)kc * 524288 + i);
    s.x += p.x; s.y += p.y; s.z += p.z; s.w += p.w;
  }
  short4v o;
  o[0] = (short)f2bf(s.x * (1.0f / 4096.0f));
  o[1] = (short)f2bf(s.y * (1.0f / 4096.0f));
  o[2] = (short)f2bf(s.z * (1.0f / 4096.0f));
  o[3] = (short)f2bf(s.w * (1.0f / 4096.0f));
  *(short4v*)(Mbf + i) = o;
}

// ---- Kernel C: PT[b][c][j] = sum_i W_w[c][i] * Mbf[b][j][i]. ----
__global__ __launch_bounds__(256) void k_pt(
    const bf16* __restrict__ Ww, const bf16* __restrict__ Mbf, bf16* __restrict__ PT)
{
  __shared__ __align__(16) char smem[16384];
  bf16* lds_a = (bf16*)smem;
  bf16* lds_b = (bf16*)(smem + 8192);
  const int ct = blockIdx.x;   // 0..7
  const int jt = blockIdx.y;   // 0..1
  const int bb = blockIdx.z;   // 0..7
  f32x4 acc[4][4];
  ACC_INIT(acc);
  mfma_loop(Ww + (size_t)ct * 128 * 256, 256,
            Mbf + ((size_t)bb * 256 + jt * 128) * 256, 256, 8, lds_a, lds_b, acc);
  const int tid = threadIdx.x, lane = tid & 63, w = tid >> 6;
  const int wr = w >> 1, wc = w & 1, quad = lane >> 4, l15 = lane & 15;
#pragma unroll
  for (int i = 0; i < 4; ++i)
#pragma unroll
    for (int j = 0; j < 4; ++j)
#pragma unroll
      for (int r = 0; r < 4; ++r) {
        int m = wr * 64 + i * 16 + quad * 4 + r;
        int n = wc * 64 + j * 16 + l15;
        PT[((size_t)bb * 1024 + ct * 128 + m) * 256 + jt * 128 + n] = __float2bfloat16(acc[i][j][r]);
      }
}

// ---- Kernel D: Wy[t][c] = sum_j theta[t][j] * PT[b][c][j]. BN stats fused (fp32 acc). ----
__global__ __launch_bounds__(256) void k_wy(
    const bf16* __restrict__ theta, const bf16* __restrict__ PT, bf16* __restrict__ Wy,
    float* __restrict__ sums, float* __restrict__ sumsq)
{
  __shared__ __align__(16) char smem[16384];
  bf16* lds_a = (bf16*)smem;
  bf16* lds_b = (bf16*)(smem + 8192);
  const size_t t0 = (size_t)blockIdx.x * 128;
  const int ct = blockIdx.y;           // 0..7
  const int bb = (int)(t0 >> 12);
  f32x4 acc[4][4];
  ACC_INIT(acc);
  mfma_loop(theta + t0 * 256, 256,
            PT + ((size_t)bb * 1024 + ct * 128) * 256, 256, 8, lds_a, lds_b, acc);
  const int tid = threadIdx.x, lane = tid & 63, w = tid >> 6;
  const int wr = w >> 1, wc = w & 1, quad = lane >> 4, l15 = lane & 15;
  float ps[4] = {0.f, 0.f, 0.f, 0.f}, pq[4] = {0.f, 0.f, 0.f, 0.f};
#pragma unroll
  for (int i = 0; i < 4; ++i)
#pragma unroll
    for (int j = 0; j < 4; ++j)
#pragma unroll
      for (int r = 0; r < 4; ++r) {
        int m = wr * 64 + i * 16 + quad * 4 + r;
        int n = wc * 64 + j * 16 + l15;
        float f = acc[i][j][r];
        Wy[(t0 + m) * 1024 + ct * 128 + n] = __float2bfloat16(f);
        ps[j] += f; pq[j] += f * f;
      }
  // quad-reduce: lanes {l15, l15+16, l15+32, l15+48} hold partials for the same channel
#pragma unroll
  for (int j = 0; j < 4; ++j) {
    ps[j] += __shfl_xor(ps[j], 16); ps[j] += __shfl_xor(ps[j], 32);
    pq[j] += __shfl_xor(pq[j], 16); pq[j] += __shfl_xor(pq[j], 32);
  }
  if (quad == 0) {
#pragma unroll
    for (int j = 0; j < 4; ++j) {
      int c = ct * 128 + wc * 64 + j * 16 + l15;
      atomicAdd(&sums[c], ps[j]);
      atomicAdd(&sumsq[c], pq[j]);
    }
  }
}

// ---- Output: BN affine computed inline from sums/sumsq (k_norm folded in). ----
// out = Wy*scale + shift + v, 4 elems/thread. sums/sumsq/gamma/beta are L2-hot.
__global__ __launch_bounds__(256) void k_out(const bf16* __restrict__ Wy, const float* __restrict__ v,
                                             const float* __restrict__ sums, const float* __restrict__ sumsq,
                                             const float* __restrict__ gamma, const float* __restrict__ beta,
                                             float* __restrict__ out)
{
  const size_t idx = ((size_t)blockIdx.x * 256 + threadIdx.x) * 4;
  const int c = (int)(idx & 1023);
  float4 sm = *(const float4*)(sums + c);
  float4 sq = *(const float4*)(sumsq + c);
  float4 gm = *(const float4*)(gamma + c);
  float4 bt = *(const float4*)(beta + c);
  short4v wv = *(const short4v*)(Wy + idx);
  float4 vv = *(const float4*)(v + idx);
  float4 o;
#pragma unroll
  for (int k = 0; k < 4; ++k) {
    float smk = (&sm.x)[k], sqk = (&sq.x)[k], gmk = (&gm.x)[k], btk = (&bt.x)[k];
    float mean = smk * (1.0f / 32768.0f);
    float var = sqk * (1.0f / 32768.0f) - mean * mean;
    float sc = gmk * rsqrtf(var + 1e-5f);
    float sh = btk - mean * sc;
    (&o.x)[k] = bf2f((unsigned short)wv[k]) * sc + sh + (&vv.x)[k];
  }
  *(float4*)(out + idx) = o;
}

extern "C" void kernel_launch(void* const* d_in, const int* in_sizes, int n_in,
                              void* d_out, int out_size, void* d_ws, size_t ws_size,
                              hipStream_t stream)
{
  (void)in_sizes; (void)n_in; (void)out_size; (void)ws_size;
  const float* v    = (const float*)d_in[0];
  const float* g_w  = (const float*)d_in[1];
  const float* g_b  = (const float*)d_in[2];
  const float* th_w = (const float*)d_in[3];
  const float* th_b = (const float*)d_in[4];
  const float* ph_w = (const float*)d_in[5];
  const float* ph_b = (const float*)d_in[6];
  const float* W_w  = (const float*)d_in[7];
  // d_in[8] = W_b: per-channel constant, exactly cancelled by BatchNorm mean. Unused.
  const float* gamma = (const float*)d_in[9];
  const float* beta  = (const float*)d_in[10];
  float* out = (float*)d_out;

  char* ws = (char*)d_ws;
  bf16* vbf  = (bf16*)ws;              // 64 MiB; dead after k_proj
  bf16* Wy   = (bf16*)ws;              // aliases vbf (written by k_wy, after k_mconv reads Mp)
  float* Mp  = (float*)ws;             // 16 MiB kc-partials; aliases dead vbf (k_affin..k_mconv)
  ws += (size_t)32768 * 1024 * 2;
  bf16* theta = (bf16*)ws;  ws += (size_t)32768 * 256 * 2;    // 16 MiB
  bf16* phiT  = (bf16*)ws;  ws += (size_t)32768 * 256 * 2;    // 16 MiB
  bf16* gT    = (bf16*)ws;  ws += (size_t)32768 * 256 * 2;    // 16 MiB
  bf16* Mbf   = (bf16*)ws;  ws += (size_t)8 * 65536 * 2;      // 1 MiB
  bf16* PT    = (bf16*)ws;  ws += (size_t)8 * 1024 * 256 * 2; // 4 MiB
  bf16* thwb  = (bf16*)ws;  ws += (size_t)256 * 1024 * 2;
  bf16* phwb  = (bf16*)ws;  ws += (size_t)256 * 1024 * 2;
  bf16* gwb   = (bf16*)ws;  ws += (size_t)256 * 1024 * 2;
  bf16* Wwb   = (bf16*)ws;  ws += (size_t)1024 * 256 * 2;
  float* sums = (float*)ws; ws += 4096;
  float* sumsq= (float*)ws; ws += 4096;

  k_cast_all<<<16384 + 512 + 1, 256, 0, stream>>>(v, vbf, th_w, ph_w, g_w, W_w,
                                                  thwb, phwb, gwb, Wwb, sums);

  k_proj <<<dim3(256, 6), 256, 0, stream>>>(vbf, thwb, th_b, phwb, ph_b, gwb, g_b, theta, phiT, gT);
  k_affin<<<dim3(8, 4, 8), 256, 0, stream>>>(phiT, gT, Mp);
  k_mconv<<<512, 256, 0, stream>>>(Mp, Mbf);
  k_pt   <<<dim3(8, 2, 8), 256, 0, stream>>>(Wwb, Mbf, PT);
  k_wy   <<<dim3(256, 8), 256, 0, stream>>>(theta, PT, Wy, sums, sumsq);
  k_out  <<<32768, 256, 0, stream>>>(Wy, v, sums, sumsq, gamma, beta, out);
}

// Round 7
// 439.160 us; speedup vs baseline: 1.0355x; 1.0269x over previous
//
#include <hip/hip_runtime.h>
#include <hip/hip_bf16.h>
#include <stdint.h>

// Rs_GCN fused pipeline, MI355X (gfx950).
// Algebra: y = (theta phi^T /N) g  ==  theta @ (phi^T g)/N  (no softmax -> associativity).
// W_y = theta @ P, P = (phi^T g) W_w^T / N.  W_b dropped (exact under BatchNorm).
// R7: k_proj tile 128x128 -> 256x128 (BM=256 tokens, BN=128 IC, BK=64, 512 thr / 8 waves,
// 64x64 per wave). Same proven 2-barrier loop; staging bytes/FLOP -25%, drains/FLOP halved
// (m93 lever). Grid 128x6 = 768 = exactly 3 CU-rounds. Transpose epilogue in two 128-token
// halves reusing the 128x133 LDS buffer. All other kernels unchanged from R6 (swizzled
// mfma_loop in k_affin/k_pt/k_wy; atomic-free affin; fused BN stats; inline BN in k_out).
// Known floors: fillBuffer re-poison ~78us (harness), k_cast ~32 (roofline), k_out ~52
// (roofline). Cross-round total attribution unreliable <10us; per-kernel dur_us only.

using bf16 = __hip_bfloat16;
typedef __attribute__((ext_vector_type(8))) short short8;
typedef __attribute__((ext_vector_type(4))) float f32x4;
typedef __attribute__((ext_vector_type(4))) short short4v;

#define DEVI static __device__ __forceinline__

DEVI float bf2f(unsigned short u) {
  union { unsigned int i; float f; } x; x.i = ((unsigned int)u) << 16; return x.f;
}
DEVI unsigned short f2bf(float f) {
  __hip_bfloat16 h = __float2bfloat16(f);
  return *reinterpret_cast<unsigned short*>(&h);
}

DEVI void gld16(const void* g, void* l) {
  __builtin_amdgcn_global_load_lds((__attribute__((address_space(1))) void*)g,
                                   (__attribute__((address_space(3))) void*)l,
                                   16, 0, 0);
}

DEVI short8 cvt8(float4 a, float4 b) {
  short8 o;
  o[0] = (short)f2bf(a.x); o[1] = (short)f2bf(a.y);
  o[2] = (short)f2bf(a.z); o[3] = (short)f2bf(a.w);
  o[4] = (short)f2bf(b.x); o[5] = (short)f2bf(b.y);
  o[6] = (short)f2bf(b.z); o[7] = (short)f2bf(b.w);
  return o;
}

// ---- 128x128 tile, BK=32, 256 thr (4 waves 2x2). Swizzled LDS (conflict-free ds_read,
// measured R3); used by the short-K kernels k_affin/k_pt/k_wy where LDS reads are on the
// critical path. ----
DEVI void mfma_loop(const bf16* A, int ldA, const bf16* B, int ldB,
                    int kiters, bf16* lds_a, bf16* lds_b, f32x4 acc[4][4])
{
  const int tid = threadIdx.x;
  const int lane = tid & 63;
  const int w = tid >> 6;
  const int wr = w >> 1, wc = w & 1;
  const int srow = w * 32 + (lane >> 2);
  const int scol = (((lane & 3) ^ ((srow >> 1) & 3))) * 8;   // source-side swizzle
  const bf16* ga0 = A + (size_t)srow * ldA + scol;
  const bf16* ga1 = A + (size_t)(srow + 16) * ldA + scol;
  const bf16* gb0 = B + (size_t)srow * ldB + scol;
  const bf16* gb1 = B + (size_t)(srow + 16) * ldB + scol;
  bf16* la0 = lds_a + w * 1024 + lane * 8;
  bf16* la1 = la0 + 512;
  bf16* lb0 = lds_b + w * 1024 + lane * 8;
  bf16* lb1 = lb0 + 512;
  const int frow = lane & 15;
  const int fk = (((lane >> 4) ^ ((frow >> 1) & 3))) * 8;    // read-side swizzle (same XOR)
  const bf16* ra = lds_a + (wr * 64 + frow) * 32 + fk;
  const bf16* rb = lds_b + (wc * 64 + frow) * 32 + fk;
  for (int it = 0; it < kiters; ++it) {
    gld16(ga0, la0); gld16(ga1, la1);
    gld16(gb0, lb0); gld16(gb1, lb1);
    ga0 += 32; ga1 += 32; gb0 += 32; gb1 += 32;
    __syncthreads();
    short8 af[4], bfr[4];
#pragma unroll
    for (int i = 0; i < 4; ++i) af[i] = *(const short8*)(ra + i * 512);
#pragma unroll
    for (int j = 0; j < 4; ++j) bfr[j] = *(const short8*)(rb + j * 512);
#pragma unroll
    for (int i = 0; i < 4; ++i)
#pragma unroll
      for (int j = 0; j < 4; ++j)
        acc[i][j] = __builtin_amdgcn_mfma_f32_16x16x32_bf16(af[i], bfr[j], acc[i][j], 0, 0, 0);
    __syncthreads();
  }
}

// ---- 256x128 tile, BK=64, 512 thr (8 waves 4Mx2N, 64x64/wave). Unswizzled (k_proj
// evidence R3). LDS k-split: A [2][256][32] (32KB), B [2][128][32] (16KB); each subtile
// is the proven 64B-row layout; gld16 dests linear, split via per-lane GLOBAL address
// permutation (rule #21). 6 gld16/thread/iter, kiters = K/64. ----
DEVI void mfma_loop_256x128(const bf16* A, int ldA, const bf16* B, int ldB,
                            int kiters64, bf16* lds_a, bf16* lds_b, f32x4 acc[4][4])
{
  const int tid = threadIdx.x;       // 0..511
  const int lane = tid & 63;
  const int w = tid >> 6;            // 0..7
  const int wr = w >> 1, wc = w & 1; // wr 0..3 (M), wc 0..1 (N)
  // A: 2048 16B-chunks (4/thread): p = s*512 + tid; ksub=p>>10, row=(p>>2)&255, c2=p&3.
  const bf16* gA[4]; bf16* dA[4];
#pragma unroll
  for (int s = 0; s < 4; ++s) {
    const int p = s * 512 + tid;
    const int ksub = p >> 10;
    const int row = (p >> 2) & 255;
    const int c2 = p & 3;
    gA[s] = A + (size_t)row * ldA + ksub * 32 + c2 * 8;
    dA[s] = lds_a + p * 8;           // = s*4096 + w*512 + lane*8 : wave-uniform + lane*16B
  }
  // B: 1024 16B-chunks (2/thread): p = s*512 + tid; ksub=p>>9, row=(p>>2)&127, c2=p&3.
  const bf16* gB[2]; bf16* dB[2];
#pragma unroll
  for (int s = 0; s < 2; ++s) {
    const int p = s * 512 + tid;
    const int ksub = p >> 9;
    const int row = (p >> 2) & 127;
    const int c2 = p & 3;
    gB[s] = B + (size_t)row * ldB + ksub * 32 + c2 * 8;
    dB[s] = lds_b + p * 8;
  }
  const int frow = lane & 15;
  const int fk = (lane >> 4) * 8;
  const bf16* ra = lds_a + (wr * 64 + frow) * 32 + fk;   // + kk*8192 + i*512
  const bf16* rb = lds_b + (wc * 64 + frow) * 32 + fk;   // + kk*4096 + j*512
  for (int it = 0; it < kiters64; ++it) {
#pragma unroll
    for (int s = 0; s < 4; ++s) gld16(gA[s], dA[s]);
#pragma unroll
    for (int s = 0; s < 2; ++s) gld16(gB[s], dB[s]);
#pragma unroll
    for (int s = 0; s < 4; ++s) gA[s] += 64;
#pragma unroll
    for (int s = 0; s < 2; ++s) gB[s] += 64;
    __syncthreads();
#pragma unroll
    for (int kk = 0; kk < 2; ++kk) {
      short8 af[4], bfr[4];
#pragma unroll
      for (int i = 0; i < 4; ++i) af[i] = *(const short8*)(ra + kk * 8192 + i * 512);
#pragma unroll
      for (int j = 0; j < 4; ++j) bfr[j] = *(const short8*)(rb + kk * 4096 + j * 512);
#pragma unroll
      for (int i = 0; i < 4; ++i)
#pragma unroll
        for (int j = 0; j < 4; ++j)
          acc[i][j] = __builtin_amdgcn_mfma_f32_16x16x32_bf16(af[i], bfr[j], acc[i][j], 0, 0, 0);
    }
    __syncthreads();
  }
}

#define ACC_INIT(acc)                                   \
  _Pragma("unroll") for (int i = 0; i < 4; ++i)         \
  _Pragma("unroll") for (int j = 0; j < 4; ++j)         \
      acc[i][j] = (f32x4){0.f, 0.f, 0.f, 0.f};

// ---- All fp32->bf16 casts in ONE launch + sums/sumsq zeroing block. ----
__global__ __launch_bounds__(256) void k_cast_all(
    const float* __restrict__ v, bf16* __restrict__ vbf,
    const float* __restrict__ s0, const float* __restrict__ s1,
    const float* __restrict__ s2, const float* __restrict__ s3,
    bf16* __restrict__ d0, bf16* __restrict__ d1,
    bf16* __restrict__ d2, bf16* __restrict__ d3,
    float* __restrict__ zbuf)
{
  const int bx = blockIdx.x;
  if (bx == 16384 + 512) {     // zero sums+sumsq: 2048 floats
    float4 z = {0.f, 0.f, 0.f, 0.f};
    *(float4*)(zbuf + threadIdx.x * 8) = z;
    *(float4*)(zbuf + threadIdx.x * 8 + 4) = z;
    return;
  }
  const float* in; bf16* out; size_t base;
  if (bx < 16384) {
    in = v; out = vbf; base = (size_t)bx * 2048;
  } else {
    const int wq = bx - 16384;
    switch (wq >> 7) {
      case 0:  in = s0; out = d0; break;
      case 1:  in = s1; out = d1; break;
      case 2:  in = s2; out = d2; break;
      default: in = s3; out = d3; break;
    }
    base = (size_t)(wq & 127) * 2048;
  }
  const size_t idx = base + (size_t)threadIdx.x * 8;
  float4 a = *(const float4*)(in + idx);
  float4 b = *(const float4*)(in + idx + 4);
  *(short8*)(out + idx) = cvt8(a, b);
}

// ---- Kernel A: projections, 256x128 tile. theta token-major; phi,g -> [b][ic][n]. ----
__global__ __launch_bounds__(512) void k_proj(
    const bf16* __restrict__ vbf,
    const bf16* __restrict__ w_th, const float* __restrict__ b_th,
    const bf16* __restrict__ w_ph, const float* __restrict__ b_ph,
    const bf16* __restrict__ w_g,  const float* __restrict__ b_g,
    bf16* __restrict__ theta, bf16* __restrict__ phiT, bf16* __restrict__ gT)
{
  __shared__ __align__(16) char smem[49152];   // staging 48KB; epilogue reuses 34048B
  bf16* lds_a = (bf16*)smem;                   // [2][256][32] = 32KB
  bf16* lds_b = (bf16*)(smem + 32768);         // [2][128][32] = 16KB
  unsigned short* lds_t = (unsigned short*)smem;  // 128x133 transpose buffer

  const int tt = blockIdx.x;        // token tile 0..127 (256 tokens each)
  const int yy = blockIdx.y;        // 0..5
  const int proj = yy >> 1;         // 0 theta, 1 phi, 2 g
  const int icb = (yy & 1) * 128;
  const bf16* wsel = (proj == 0) ? w_th : ((proj == 1) ? w_ph : w_g);
  const float* bsel = (proj == 0) ? b_th : ((proj == 1) ? b_ph : b_g);

  const size_t t0 = (size_t)tt * 256;
  f32x4 acc[4][4];
  ACC_INIT(acc);
  mfma_loop_256x128(vbf + t0 * 1024, 1024, wsel + (size_t)icb * 1024, 1024, 16,
                    lds_a, lds_b, acc);

  const int tid = threadIdx.x, lane = tid & 63, w = tid >> 6;
  const int wr = w >> 1, wc = w & 1, quad = lane >> 4, l15 = lane & 15;
  float biasv[4];
#pragma unroll
  for (int j = 0; j < 4; ++j) biasv[j] = bsel[icb + wc * 64 + j * 16 + l15];

  if (proj == 0) {
#pragma unroll
    for (int i = 0; i < 4; ++i)
#pragma unroll
      for (int j = 0; j < 4; ++j)
#pragma unroll
        for (int r = 0; r < 4; ++r) {
          int m = wr * 64 + i * 16 + quad * 4 + r;       // 0..255
          int n = wc * 64 + j * 16 + l15;                // 0..127
          theta[(t0 + m) * 256 + icb + n] = __float2bfloat16(acc[i][j][r] + biasv[j]);
        }
  } else {
    bf16* outT = (proj == 1) ? phiT : gT;
    const int bb = (int)(t0 >> 12);
    const int n0 = (int)(t0 & 4095);
    const int tg = tid & 15;       // 16 token-groups x 8 tokens
    const int ch0 = tid >> 4;      // 0..31
#pragma unroll
    for (int h = 0; h < 2; ++h) {  // two 128-token halves share the 128x133 buffer
      __syncthreads();
      if ((wr >> 1) == h) {        // waves 0-3 own tokens 0..127; waves 4-7 own 128..255
#pragma unroll
        for (int i = 0; i < 4; ++i)
#pragma unroll
          for (int j = 0; j < 4; ++j)
#pragma unroll
            for (int r = 0; r < 4; ++r) {
              int mrow = (wr & 1) * 64 + i * 16 + quad * 4 + r;  // 0..127 within half
              int n = wc * 64 + j * 16 + l15;
              lds_t[mrow * 133 + n] = f2bf(acc[i][j][r] + biasv[j]);
            }
      }
      __syncthreads();
#pragma unroll
      for (int cc = 0; cc < 4; ++cc) {
        int ch = ch0 + cc * 32;
        short8 pk;
#pragma unroll
        for (int r = 0; r < 8; ++r) pk[r] = (short)lds_t[(tg * 8 + r) * 133 + ch];
        *(short8*)(outT + ((size_t)(bb * 256 + icb + ch)) * 4096 + n0 + h * 128 + tg * 8) = pk;
      }
    }
  }
}

// ---- Kernel B: Mp[kc][b] = phi[kc-chunk]^T g[kc-chunk], plain stores (atomic-free). ----
__global__ __launch_bounds__(256) void k_affin(
    const bf16* __restrict__ phiT, const bf16* __restrict__ gT, float* __restrict__ Mp)
{
  __shared__ __align__(16) char smem[16384];
  bf16* lds_a = (bf16*)smem;
  bf16* lds_b = (bf16*)(smem + 8192);
  const int kc = blockIdx.x;        // 0..7 K-chunk
  const int jt = blockIdx.y >> 1;   // 0..1
  const int it2 = blockIdx.y & 1;   // 0..1
  const int bb = blockIdx.z;        // 0..7
  f32x4 acc[4][4];
  ACC_INIT(acc);
  const bf16* A = phiT + ((size_t)bb * 256 + jt * 128) * 4096 + kc * 512;
  const bf16* B = gT   + ((size_t)bb * 256 + it2 * 128) * 4096 + kc * 512;
  mfma_loop(A, 4096, B, 4096, 16, lds_a, lds_b, acc);
  const int tid = threadIdx.x, lane = tid & 63, w = tid >> 6;
  const int wr = w >> 1, wc = w & 1, quad = lane >> 4, l15 = lane & 15;
  float* Mb = Mp + ((size_t)kc * 8 + bb) * 65536;
#pragma unroll
  for (int i = 0; i < 4; ++i)
#pragma unroll
    for (int j = 0; j < 4; ++j)
#pragma unroll
      for (int r = 0; r < 4; ++r) {
        int m = wr * 64 + i * 16 + quad * 4 + r;
        int n = wc * 64 + j * 16 + l15;
        Mb[(size_t)(jt * 128 + m) * 256 + it2 * 128 + n] = acc[i][j][r];
      }
}

// ---- Reduce 8 kc-partials -> bf16, folding the 1/N affinity normalization. ----
__global__ __launch_bounds__(256) void k_mconv(const float* __restrict__ Mp, bf16* __restrict__ Mbf)
{
  const size_t i = ((size_t)blockIdx.x * 256 + threadIdx.x) * 4;   // 524288 elems / 4
  float4 s = *(const float4*)(Mp + i);
#pragma unroll
  for (int kc = 1; kc < 8; ++kc) {
    float4 p = *(const float4*)(Mp + (size_t)kc * 524288 + i);
    s.x += p.x; s.y += p.y; s.z += p.z; s.w += p.w;
  }
  short4v o;
  o[0] = (short)f2bf(s.x * (1.0f / 4096.0f));
  o[1] = (short)f2bf(s.y * (1.0f / 4096.0f));
  o[2] = (short)f2bf(s.z * (1.0f / 4096.0f));
  o[3] = (short)f2bf(s.w * (1.0f / 4096.0f));
  *(short4v*)(Mbf + i) = o;
}

// ---- Kernel C: PT[b][c][j] = sum_i W_w[c][i] * Mbf[b][j][i]. ----
__global__ __launch_bounds__(256) void k_pt(
    const bf16* __restrict__ Ww, const bf16* __restrict__ Mbf, bf16* __restrict__ PT)
{
  __shared__ __align__(16) char smem[16384];
  bf16* lds_a = (bf16*)smem;
  bf16* lds_b = (bf16*)(smem + 8192);
  const int ct = blockIdx.x;   // 0..7
  const int jt = blockIdx.y;   // 0..1
  const int bb = blockIdx.z;   // 0..7
  f32x4 acc[4][4];
  ACC_INIT(acc);
  mfma_loop(Ww + (size_t)ct * 128 * 256, 256,
            Mbf + ((size_t)bb * 256 + jt * 128) * 256, 256, 8, lds_a, lds_b, acc);
  const int tid = threadIdx.x, lane = tid & 63, w = tid >> 6;
  const int wr = w >> 1, wc = w & 1, quad = lane >> 4, l15 = lane & 15;
#pragma unroll
  for (int i = 0; i < 4; ++i)
#pragma unroll
    for (int j = 0; j < 4; ++j)
#pragma unroll
      for (int r = 0; r < 4; ++r) {
        int m = wr * 64 + i * 16 + quad * 4 + r;
        int n = wc * 64 + j * 16 + l15;
        PT[((size_t)bb * 1024 + ct * 128 + m) * 256 + jt * 128 + n] = __float2bfloat16(acc[i][j][r]);
      }
}

// ---- Kernel D: Wy[t][c] = sum_j theta[t][j] * PT[b][c][j]. BN stats fused (fp32 acc). ----
__global__ __launch_bounds__(256) void k_wy(
    const bf16* __restrict__ theta, const bf16* __restrict__ PT, bf16* __restrict__ Wy,
    float* __restrict__ sums, float* __restrict__ sumsq)
{
  __shared__ __align__(16) char smem[16384];
  bf16* lds_a = (bf16*)smem;
  bf16* lds_b = (bf16*)(smem + 8192);
  const size_t t0 = (size_t)blockIdx.x * 128;
  const int ct = blockIdx.y;           // 0..7
  const int bb = (int)(t0 >> 12);
  f32x4 acc[4][4];
  ACC_INIT(acc);
  mfma_loop(theta + t0 * 256, 256,
            PT + ((size_t)bb * 1024 + ct * 128) * 256, 256, 8, lds_a, lds_b, acc);
  const int tid = threadIdx.x, lane = tid & 63, w = tid >> 6;
  const int wr = w >> 1, wc = w & 1, quad = lane >> 4, l15 = lane & 15;
  float ps[4] = {0.f, 0.f, 0.f, 0.f}, pq[4] = {0.f, 0.f, 0.f, 0.f};
#pragma unroll
  for (int i = 0; i < 4; ++i)
#pragma unroll
    for (int j = 0; j < 4; ++j)
#pragma unroll
      for (int r = 0; r < 4; ++r) {
        int m = wr * 64 + i * 16 + quad * 4 + r;
        int n = wc * 64 + j * 16 + l15;
        float f = acc[i][j][r];
        Wy[(t0 + m) * 1024 + ct * 128 + n] = __float2bfloat16(f);
        ps[j] += f; pq[j] += f * f;
      }
#pragma unroll
  for (int j = 0; j < 4; ++j) {
    ps[j] += __shfl_xor(ps[j], 16); ps[j] += __shfl_xor(ps[j], 32);
    pq[j] += __shfl_xor(pq[j], 16); pq[j] += __shfl_xor(pq[j], 32);
  }
  if (quad == 0) {
#pragma unroll
    for (int j = 0; j < 4; ++j) {
      int c = ct * 128 + wc * 64 + j * 16 + l15;
      atomicAdd(&sums[c], ps[j]);
      atomicAdd(&sumsq[c], pq[j]);
    }
  }
}

// ---- Output: BN affine computed inline from sums/sumsq. out = Wy*scale + shift + v. ----
__global__ __launch_bounds__(256) void k_out(const bf16* __restrict__ Wy, const float* __restrict__ v,
                                             const float* __restrict__ sums, const float* __restrict__ sumsq,
                                             const float* __restrict__ gamma, const float* __restrict__ beta,
                                             float* __restrict__ out)
{
  const size_t idx = ((size_t)blockIdx.x * 256 + threadIdx.x) * 4;
  const int c = (int)(idx & 1023);
  float4 sm = *(const float4*)(sums + c);
  float4 sq = *(const float4*)(sumsq + c);
  float4 gm = *(const float4*)(gamma + c);
  float4 bt = *(const float4*)(beta + c);
  short4v wv = *(const short4v*)(Wy + idx);
  float4 vv = *(const float4*)(v + idx);
  float4 o;
#pragma unroll
  for (int k = 0; k < 4; ++k) {
    float smk = (&sm.x)[k], sqk = (&sq.x)[k], gmk = (&gm.x)[k], btk = (&bt.x)[k];
    float mean = smk * (1.0f / 32768.0f);
    float var = sqk * (1.0f / 32768.0f) - mean * mean;
    float sc = gmk * rsqrtf(var + 1e-5f);
    float sh = btk - mean * sc;
    (&o.x)[k] = bf2f((unsigned short)wv[k]) * sc + sh + (&vv.x)[k];
  }
  *(float4*)(out + idx) = o;
}

extern "C" void kernel_launch(void* const* d_in, const int* in_sizes, int n_in,
                              void* d_out, int out_size, void* d_ws, size_t ws_size,
                              hipStream_t stream)
{
  (void)in_sizes; (void)n_in; (void)out_size; (void)ws_size;
  const float* v    = (const float*)d_in[0];
  const float* g_w  = (const float*)d_in[1];
  const float* g_b  = (const float*)d_in[2];
  const float* th_w = (const float*)d_in[3];
  const float* th_b = (const float*)d_in[4];
  const float* ph_w = (const float*)d_in[5];
  const float* ph_b = (const float*)d_in[6];
  const float* W_w  = (const float*)d_in[7];
  // d_in[8] = W_b: per-channel constant, exactly cancelled by BatchNorm mean. Unused.
  const float* gamma = (const float*)d_in[9];
  const float* beta  = (const float*)d_in[10];
  float* out = (float*)d_out;

  char* ws = (char*)d_ws;
  bf16* vbf  = (bf16*)ws;              // 64 MiB; dead after k_proj
  bf16* Wy   = (bf16*)ws;              // aliases vbf (written by k_wy, after k_mconv reads Mp)
  float* Mp  = (float*)ws;             // 16 MiB kc-partials; aliases dead vbf
  ws += (size_t)32768 * 1024 * 2;
  bf16* theta = (bf16*)ws;  ws += (size_t)32768 * 256 * 2;    // 16 MiB
  bf16* phiT  = (bf16*)ws;  ws += (size_t)32768 * 256 * 2;    // 16 MiB
  bf16* gT    = (bf16*)ws;  ws += (size_t)32768 * 256 * 2;    // 16 MiB
  bf16* Mbf   = (bf16*)ws;  ws += (size_t)8 * 65536 * 2;      // 1 MiB
  bf16* PT    = (bf16*)ws;  ws += (size_t)8 * 1024 * 256 * 2; // 4 MiB
  bf16* thwb  = (bf16*)ws;  ws += (size_t)256 * 1024 * 2;
  bf16* phwb  = (bf16*)ws;  ws += (size_t)256 * 1024 * 2;
  bf16* gwb   = (bf16*)ws;  ws += (size_t)256 * 1024 * 2;
  bf16* Wwb   = (bf16*)ws;  ws += (size_t)1024 * 256 * 2;
  float* sums = (float*)ws; ws += 4096;
  float* sumsq= (float*)ws; ws += 4096;

  k_cast_all<<<16384 + 512 + 1, 256, 0, stream>>>(v, vbf, th_w, ph_w, g_w, W_w,
                                                  thwb, phwb, gwb, Wwb, sums);

  k_proj <<<dim3(128, 6), 512, 0, stream>>>(vbf, thwb, th_b, phwb, ph_b, gwb, g_b, theta, phiT, gT);
  k_affin<<<dim3(8, 4, 8), 256, 0, stream>>>(phiT, gT, Mp);
  k_mconv<<<512, 256, 0, stream>>>(Mp, Mbf);
  k_pt   <<<dim3(8, 2, 8), 256, 0, stream>>>(Wwb, Mbf, PT);
  k_wy   <<<dim3(256, 8), 256, 0, stream>>>(theta, PT, Wy, sums, sumsq);
  k_out  <<<32768, 256, 0, stream>>>(Wy, v, sums, sumsq, gamma, beta, out);
}

// Round 8
// 415.959 us; speedup vs baseline: 1.0933x; 1.0558x over previous
//
#include <hip/hip_runtime.h>
#include <hip/hip_bf16.h>
#include <stdint.h>

// Rs_GCN fused pipeline, MI355X (gfx950).
// Algebra: y = (theta phi^T /N) g  ==  theta @ (phi^T g)/N  (no softmax -> associativity).
// W_y = theta @ P, P = (phi^T g) W_w^T / N.  W_b dropped (exact under BatchNorm).
// R8: k_wy moves to the 256x128/BK64/512-thr loop proven on k_proj in R7 (staging/FLOP
// -25%, drains/FLOP halved; k_proj hit the m97 2-barrier ceiling ~858TF with it). BN-stat
// atomics cut 4x via cross-wave LDS reduce (1 add per channel per block). All else = R7.
// Budget: fill ~78 (harness), k_cast ~31 (roofline), k_proj ~60 (2-barrier ceiling),
// k_out ~52 (roofline), k_wy ~30->20 (this round), affin/mconv/pt ~19.

using bf16 = __hip_bfloat16;
typedef __attribute__((ext_vector_type(8))) short short8;
typedef __attribute__((ext_vector_type(4))) float f32x4;
typedef __attribute__((ext_vector_type(4))) short short4v;

#define DEVI static __device__ __forceinline__

DEVI float bf2f(unsigned short u) {
  union { unsigned int i; float f; } x; x.i = ((unsigned int)u) << 16; return x.f;
}
DEVI unsigned short f2bf(float f) {
  __hip_bfloat16 h = __float2bfloat16(f);
  return *reinterpret_cast<unsigned short*>(&h);
}

DEVI void gld16(const void* g, void* l) {
  __builtin_amdgcn_global_load_lds((__attribute__((address_space(1))) void*)g,
                                   (__attribute__((address_space(3))) void*)l,
                                   16, 0, 0);
}

DEVI short8 cvt8(float4 a, float4 b) {
  short8 o;
  o[0] = (short)f2bf(a.x); o[1] = (short)f2bf(a.y);
  o[2] = (short)f2bf(a.z); o[3] = (short)f2bf(a.w);
  o[4] = (short)f2bf(b.x); o[5] = (short)f2bf(b.y);
  o[6] = (short)f2bf(b.z); o[7] = (short)f2bf(b.w);
  return o;
}

// ---- 128x128 tile, BK=32, 256 thr (4 waves 2x2). Swizzled LDS (conflict-free ds_read,
// measured R3); used by short-K kernels k_affin/k_pt. ----
DEVI void mfma_loop(const bf16* A, int ldA, const bf16* B, int ldB,
                    int kiters, bf16* lds_a, bf16* lds_b, f32x4 acc[4][4])
{
  const int tid = threadIdx.x;
  const int lane = tid & 63;
  const int w = tid >> 6;
  const int wr = w >> 1, wc = w & 1;
  const int srow = w * 32 + (lane >> 2);
  const int scol = (((lane & 3) ^ ((srow >> 1) & 3))) * 8;   // source-side swizzle
  const bf16* ga0 = A + (size_t)srow * ldA + scol;
  const bf16* ga1 = A + (size_t)(srow + 16) * ldA + scol;
  const bf16* gb0 = B + (size_t)srow * ldB + scol;
  const bf16* gb1 = B + (size_t)(srow + 16) * ldB + scol;
  bf16* la0 = lds_a + w * 1024 + lane * 8;
  bf16* la1 = la0 + 512;
  bf16* lb0 = lds_b + w * 1024 + lane * 8;
  bf16* lb1 = lb0 + 512;
  const int frow = lane & 15;
  const int fk = (((lane >> 4) ^ ((frow >> 1) & 3))) * 8;    // read-side swizzle (same XOR)
  const bf16* ra = lds_a + (wr * 64 + frow) * 32 + fk;
  const bf16* rb = lds_b + (wc * 64 + frow) * 32 + fk;
  for (int it = 0; it < kiters; ++it) {
    gld16(ga0, la0); gld16(ga1, la1);
    gld16(gb0, lb0); gld16(gb1, lb1);
    ga0 += 32; ga1 += 32; gb0 += 32; gb1 += 32;
    __syncthreads();
    short8 af[4], bfr[4];
#pragma unroll
    for (int i = 0; i < 4; ++i) af[i] = *(const short8*)(ra + i * 512);
#pragma unroll
    for (int j = 0; j < 4; ++j) bfr[j] = *(const short8*)(rb + j * 512);
#pragma unroll
    for (int i = 0; i < 4; ++i)
#pragma unroll
      for (int j = 0; j < 4; ++j)
        acc[i][j] = __builtin_amdgcn_mfma_f32_16x16x32_bf16(af[i], bfr[j], acc[i][j], 0, 0, 0);
    __syncthreads();
  }
}

// ---- 256x128 tile, BK=64, 512 thr (8 waves 4Mx2N, 64x64/wave). Unswizzled. LDS k-split:
// A [2][256][32] (32KB), B [2][128][32] (16KB); subtiles keep the proven 64B-row layout;
// gld16 dests linear, split via per-lane GLOBAL address permutation (rule #21). ----
DEVI void mfma_loop_256x128(const bf16* A, int ldA, const bf16* B, int ldB,
                            int kiters64, bf16* lds_a, bf16* lds_b, f32x4 acc[4][4])
{
  const int tid = threadIdx.x;       // 0..511
  const int lane = tid & 63;
  const int w = tid >> 6;            // 0..7
  const int wr = w >> 1, wc = w & 1; // wr 0..3 (M), wc 0..1 (N)
  const bf16* gA[4]; bf16* dA[4];
#pragma unroll
  for (int s = 0; s < 4; ++s) {
    const int p = s * 512 + tid;
    const int ksub = p >> 10;
    const int row = (p >> 2) & 255;
    const int c2 = p & 3;
    gA[s] = A + (size_t)row * ldA + ksub * 32 + c2 * 8;
    dA[s] = lds_a + p * 8;           // wave-uniform base + lane*16B
  }
  const bf16* gB[2]; bf16* dB[2];
#pragma unroll
  for (int s = 0; s < 2; ++s) {
    const int p = s * 512 + tid;
    const int ksub = p >> 9;
    const int row = (p >> 2) & 127;
    const int c2 = p & 3;
    gB[s] = B + (size_t)row * ldB + ksub * 32 + c2 * 8;
    dB[s] = lds_b + p * 8;
  }
  const int frow = lane & 15;
  const int fk = (lane >> 4) * 8;
  const bf16* ra = lds_a + (wr * 64 + frow) * 32 + fk;   // + kk*8192 + i*512
  const bf16* rb = lds_b + (wc * 64 + frow) * 32 + fk;   // + kk*4096 + j*512
  for (int it = 0; it < kiters64; ++it) {
#pragma unroll
    for (int s = 0; s < 4; ++s) gld16(gA[s], dA[s]);
#pragma unroll
    for (int s = 0; s < 2; ++s) gld16(gB[s], dB[s]);
#pragma unroll
    for (int s = 0; s < 4; ++s) gA[s] += 64;
#pragma unroll
    for (int s = 0; s < 2; ++s) gB[s] += 64;
    __syncthreads();
#pragma unroll
    for (int kk = 0; kk < 2; ++kk) {
      short8 af[4], bfr[4];
#pragma unroll
      for (int i = 0; i < 4; ++i) af[i] = *(const short8*)(ra + kk * 8192 + i * 512);
#pragma unroll
      for (int j = 0; j < 4; ++j) bfr[j] = *(const short8*)(rb + kk * 4096 + j * 512);
#pragma unroll
      for (int i = 0; i < 4; ++i)
#pragma unroll
        for (int j = 0; j < 4; ++j)
          acc[i][j] = __builtin_amdgcn_mfma_f32_16x16x32_bf16(af[i], bfr[j], acc[i][j], 0, 0, 0);
    }
    __syncthreads();
  }
}

#define ACC_INIT(acc)                                   \
  _Pragma("unroll") for (int i = 0; i < 4; ++i)         \
  _Pragma("unroll") for (int j = 0; j < 4; ++j)         \
      acc[i][j] = (f32x4){0.f, 0.f, 0.f, 0.f};

// ---- All fp32->bf16 casts in ONE launch + sums/sumsq zeroing block. ----
__global__ __launch_bounds__(256) void k_cast_all(
    const float* __restrict__ v, bf16* __restrict__ vbf,
    const float* __restrict__ s0, const float* __restrict__ s1,
    const float* __restrict__ s2, const float* __restrict__ s3,
    bf16* __restrict__ d0, bf16* __restrict__ d1,
    bf16* __restrict__ d2, bf16* __restrict__ d3,
    float* __restrict__ zbuf)
{
  const int bx = blockIdx.x;
  if (bx == 16384 + 512) {     // zero sums+sumsq: 2048 floats
    float4 z = {0.f, 0.f, 0.f, 0.f};
    *(float4*)(zbuf + threadIdx.x * 8) = z;
    *(float4*)(zbuf + threadIdx.x * 8 + 4) = z;
    return;
  }
  const float* in; bf16* out; size_t base;
  if (bx < 16384) {
    in = v; out = vbf; base = (size_t)bx * 2048;
  } else {
    const int wq = bx - 16384;
    switch (wq >> 7) {
      case 0:  in = s0; out = d0; break;
      case 1:  in = s1; out = d1; break;
      case 2:  in = s2; out = d2; break;
      default: in = s3; out = d3; break;
    }
    base = (size_t)(wq & 127) * 2048;
  }
  const size_t idx = base + (size_t)threadIdx.x * 8;
  float4 a = *(const float4*)(in + idx);
  float4 b = *(const float4*)(in + idx + 4);
  *(short8*)(out + idx) = cvt8(a, b);
}

// ---- Kernel A: projections, 256x128 tile. theta token-major; phi,g -> [b][ic][n]. ----
__global__ __launch_bounds__(512) void k_proj(
    const bf16* __restrict__ vbf,
    const bf16* __restrict__ w_th, const float* __restrict__ b_th,
    const bf16* __restrict__ w_ph, const float* __restrict__ b_ph,
    const bf16* __restrict__ w_g,  const float* __restrict__ b_g,
    bf16* __restrict__ theta, bf16* __restrict__ phiT, bf16* __restrict__ gT)
{
  __shared__ __align__(16) char smem[49152];   // staging 48KB; epilogue reuses 34048B
  bf16* lds_a = (bf16*)smem;                   // [2][256][32] = 32KB
  bf16* lds_b = (bf16*)(smem + 32768);         // [2][128][32] = 16KB
  unsigned short* lds_t = (unsigned short*)smem;  // 128x133 transpose buffer

  const int tt = blockIdx.x;        // token tile 0..127 (256 tokens each)
  const int yy = blockIdx.y;        // 0..5
  const int proj = yy >> 1;         // 0 theta, 1 phi, 2 g
  const int icb = (yy & 1) * 128;
  const bf16* wsel = (proj == 0) ? w_th : ((proj == 1) ? w_ph : w_g);
  const float* bsel = (proj == 0) ? b_th : ((proj == 1) ? b_ph : b_g);

  const size_t t0 = (size_t)tt * 256;
  f32x4 acc[4][4];
  ACC_INIT(acc);
  mfma_loop_256x128(vbf + t0 * 1024, 1024, wsel + (size_t)icb * 1024, 1024, 16,
                    lds_a, lds_b, acc);

  const int tid = threadIdx.x, lane = tid & 63, w = tid >> 6;
  const int wr = w >> 1, wc = w & 1, quad = lane >> 4, l15 = lane & 15;
  float biasv[4];
#pragma unroll
  for (int j = 0; j < 4; ++j) biasv[j] = bsel[icb + wc * 64 + j * 16 + l15];

  if (proj == 0) {
#pragma unroll
    for (int i = 0; i < 4; ++i)
#pragma unroll
      for (int j = 0; j < 4; ++j)
#pragma unroll
        for (int r = 0; r < 4; ++r) {
          int m = wr * 64 + i * 16 + quad * 4 + r;       // 0..255
          int n = wc * 64 + j * 16 + l15;                // 0..127
          theta[(t0 + m) * 256 + icb + n] = __float2bfloat16(acc[i][j][r] + biasv[j]);
        }
  } else {
    bf16* outT = (proj == 1) ? phiT : gT;
    const int bb = (int)(t0 >> 12);
    const int n0 = (int)(t0 & 4095);
    const int tg = tid & 15;       // 16 token-groups x 8 tokens
    const int ch0 = tid >> 4;      // 0..31
#pragma unroll
    for (int h = 0; h < 2; ++h) {  // two 128-token halves share the 128x133 buffer
      __syncthreads();
      if ((wr >> 1) == h) {        // waves 0-3 own tokens 0..127; waves 4-7 own 128..255
#pragma unroll
        for (int i = 0; i < 4; ++i)
#pragma unroll
          for (int j = 0; j < 4; ++j)
#pragma unroll
            for (int r = 0; r < 4; ++r) {
              int mrow = (wr & 1) * 64 + i * 16 + quad * 4 + r;  // 0..127 within half
              int n = wc * 64 + j * 16 + l15;
              lds_t[mrow * 133 + n] = f2bf(acc[i][j][r] + biasv[j]);
            }
      }
      __syncthreads();
#pragma unroll
      for (int cc = 0; cc < 4; ++cc) {
        int ch = ch0 + cc * 32;
        short8 pk;
#pragma unroll
        for (int r = 0; r < 8; ++r) pk[r] = (short)lds_t[(tg * 8 + r) * 133 + ch];
        *(short8*)(outT + ((size_t)(bb * 256 + icb + ch)) * 4096 + n0 + h * 128 + tg * 8) = pk;
      }
    }
  }
}

// ---- Kernel B: Mp[kc][b] = phi[kc-chunk]^T g[kc-chunk], plain stores (atomic-free). ----
__global__ __launch_bounds__(256) void k_affin(
    const bf16* __restrict__ phiT, const bf16* __restrict__ gT, float* __restrict__ Mp)
{
  __shared__ __align__(16) char smem[16384];
  bf16* lds_a = (bf16*)smem;
  bf16* lds_b = (bf16*)(smem + 8192);
  const int kc = blockIdx.x;        // 0..7 K-chunk
  const int jt = blockIdx.y >> 1;   // 0..1
  const int it2 = blockIdx.y & 1;   // 0..1
  const int bb = blockIdx.z;        // 0..7
  f32x4 acc[4][4];
  ACC_INIT(acc);
  const bf16* A = phiT + ((size_t)bb * 256 + jt * 128) * 4096 + kc * 512;
  const bf16* B = gT   + ((size_t)bb * 256 + it2 * 128) * 4096 + kc * 512;
  mfma_loop(A, 4096, B, 4096, 16, lds_a, lds_b, acc);
  const int tid = threadIdx.x, lane = tid & 63, w = tid >> 6;
  const int wr = w >> 1, wc = w & 1, quad = lane >> 4, l15 = lane & 15;
  float* Mb = Mp + ((size_t)kc * 8 + bb) * 65536;
#pragma unroll
  for (int i = 0; i < 4; ++i)
#pragma unroll
    for (int j = 0; j < 4; ++j)
#pragma unroll
      for (int r = 0; r < 4; ++r) {
        int m = wr * 64 + i * 16 + quad * 4 + r;
        int n = wc * 64 + j * 16 + l15;
        Mb[(size_t)(jt * 128 + m) * 256 + it2 * 128 + n] = acc[i][j][r];
      }
}

// ---- Reduce 8 kc-partials -> bf16, folding the 1/N affinity normalization. ----
__global__ __launch_bounds__(256) void k_mconv(const float* __restrict__ Mp, bf16* __restrict__ Mbf)
{
  const size_t i = ((size_t)blockIdx.x * 256 + threadIdx.x) * 4;   // 524288 elems / 4
  float4 s = *(const float4*)(Mp + i);
#pragma unroll
  for (int kc = 1; kc < 8; ++kc) {
    float4 p = *(const float4*)(Mp + (size_t)kc * 524288 + i);
    s.x += p.x; s.y += p.y; s.z += p.z; s.w += p.w;
  }
  short4v o;
  o[0] = (short)f2bf(s.x * (1.0f / 4096.0f));
  o[1] = (short)f2bf(s.y * (1.0f / 4096.0f));
  o[2] = (short)f2bf(s.z * (1.0f / 4096.0f));
  o[3] = (short)f2bf(s.w * (1.0f / 4096.0f));
  *(short4v*)(Mbf + i) = o;
}

// ---- Kernel C: PT[b][c][j] = sum_i W_w[c][i] * Mbf[b][j][i]. ----
__global__ __launch_bounds__(256) void k_pt(
    const bf16* __restrict__ Ww, const bf16* __restrict__ Mbf, bf16* __restrict__ PT)
{
  __shared__ __align__(16) char smem[16384];
  bf16* lds_a = (bf16*)smem;
  bf16* lds_b = (bf16*)(smem + 8192);
  const int ct = blockIdx.x;   // 0..7
  const int jt = blockIdx.y;   // 0..1
  const int bb = blockIdx.z;   // 0..7
  f32x4 acc[4][4];
  ACC_INIT(acc);
  mfma_loop(Ww + (size_t)ct * 128 * 256, 256,
            Mbf + ((size_t)bb * 256 + jt * 128) * 256, 256, 8, lds_a, lds_b, acc);
  const int tid = threadIdx.x, lane = tid & 63, w = tid >> 6;
  const int wr = w >> 1, wc = w & 1, quad = lane >> 4, l15 = lane & 15;
#pragma unroll
  for (int i = 0; i < 4; ++i)
#pragma unroll
    for (int j = 0; j < 4; ++j)
#pragma unroll
      for (int r = 0; r < 4; ++r) {
        int m = wr * 64 + i * 16 + quad * 4 + r;
        int n = wc * 64 + j * 16 + l15;
        PT[((size_t)bb * 1024 + ct * 128 + m) * 256 + jt * 128 + n] = __float2bfloat16(acc[i][j][r]);
      }
}

// ---- Kernel D: Wy[t][c] = sum_j theta[t][j] * PT[b][c][j], 256x128 tile / 512 thr.
// BN stats fused: per-wave quad-reduce -> cross-wave LDS reduce -> 1 atomic per channel
// per block (atomics 4x down vs per-wave adds). ----
__global__ __launch_bounds__(512) void k_wy(
    const bf16* __restrict__ theta, const bf16* __restrict__ PT, bf16* __restrict__ Wy,
    float* __restrict__ sums, float* __restrict__ sumsq)
{
  __shared__ __align__(16) char smem[49152];   // staging 48KB; stats reduce reuses 4KB
  bf16* lds_a = (bf16*)smem;                   // [2][256][32]
  bf16* lds_b = (bf16*)(smem + 32768);         // [2][128][32]
  const size_t t0 = (size_t)blockIdx.x * 256;  // token tile (128 tiles)
  const int ct = blockIdx.y;                   // 0..7
  const int bb = (int)(t0 >> 12);
  f32x4 acc[4][4];
  ACC_INIT(acc);
  mfma_loop_256x128(theta + t0 * 256, 256,
                    PT + ((size_t)bb * 1024 + ct * 128) * 256, 256, 4, lds_a, lds_b, acc);
  const int tid = threadIdx.x, lane = tid & 63, w = tid >> 6;
  const int wr = w >> 1, wc = w & 1, quad = lane >> 4, l15 = lane & 15;
  float ps[4] = {0.f, 0.f, 0.f, 0.f}, pq[4] = {0.f, 0.f, 0.f, 0.f};
#pragma unroll
  for (int i = 0; i < 4; ++i)
#pragma unroll
    for (int j = 0; j < 4; ++j)
#pragma unroll
      for (int r = 0; r < 4; ++r) {
        int m = wr * 64 + i * 16 + quad * 4 + r;   // 0..255
        int n = wc * 64 + j * 16 + l15;            // 0..127
        float f = acc[i][j][r];
        Wy[(t0 + m) * 1024 + ct * 128 + n] = __float2bfloat16(f);
        ps[j] += f; pq[j] += f * f;
      }
  // quad-reduce: lanes {l15, +16, +32, +48} hold partials for the same channel
#pragma unroll
  for (int j = 0; j < 4; ++j) {
    ps[j] += __shfl_xor(ps[j], 16); ps[j] += __shfl_xor(ps[j], 32);
    pq[j] += __shfl_xor(pq[j], 16); pq[j] += __shfl_xor(pq[j], 32);
  }
  // cross-wave reduce in (dead staging) LDS: sred/sqred [8 waves][64 channels]
  float* sred = (float*)smem;
  float* sqred = sred + 512;
  if (quad == 0) {
#pragma unroll
    for (int j = 0; j < 4; ++j) {
      sred[w * 64 + j * 16 + l15] = ps[j];
      sqred[w * 64 + j * 16 + l15] = pq[j];
    }
  }
  __syncthreads();
  if (tid < 128) {                       // sums: 2 wc x 64 ch
    const int wc2 = tid >> 6, ch = tid & 63;
    float s = sred[(wc2 + 0) * 64 + ch] + sred[(wc2 + 2) * 64 + ch]
            + sred[(wc2 + 4) * 64 + ch] + sred[(wc2 + 6) * 64 + ch];
    atomicAdd(&sums[ct * 128 + wc2 * 64 + ch], s);
  } else if (tid < 256) {                // sumsq
    const int t2 = tid - 128;
    const int wc2 = t2 >> 6, ch = t2 & 63;
    float q = sqred[(wc2 + 0) * 64 + ch] + sqred[(wc2 + 2) * 64 + ch]
            + sqred[(wc2 + 4) * 64 + ch] + sqred[(wc2 + 6) * 64 + ch];
    atomicAdd(&sumsq[ct * 128 + wc2 * 64 + ch], q);
  }
}

// ---- Output: BN affine computed inline from sums/sumsq. out = Wy*scale + shift + v. ----
__global__ __launch_bounds__(256) void k_out(const bf16* __restrict__ Wy, const float* __restrict__ v,
                                             const float* __restrict__ sums, const float* __restrict__ sumsq,
                                             const float* __restrict__ gamma, const float* __restrict__ beta,
                                             float* __restrict__ out)
{
  const size_t idx = ((size_t)blockIdx.x * 256 + threadIdx.x) * 4;
  const int c = (int)(idx & 1023);
  float4 sm = *(const float4*)(sums + c);
  float4 sq = *(const float4*)(sumsq + c);
  float4 gm = *(const float4*)(gamma + c);
  float4 bt = *(const float4*)(beta + c);
  short4v wv = *(const short4v*)(Wy + idx);
  float4 vv = *(const float4*)(v + idx);
  float4 o;
#pragma unroll
  for (int k = 0; k < 4; ++k) {
    float smk = (&sm.x)[k], sqk = (&sq.x)[k], gmk = (&gm.x)[k], btk = (&bt.x)[k];
    float mean = smk * (1.0f / 32768.0f);
    float var = sqk * (1.0f / 32768.0f) - mean * mean;
    float sc = gmk * rsqrtf(var + 1e-5f);
    float sh = btk - mean * sc;
    (&o.x)[k] = bf2f((unsigned short)wv[k]) * sc + sh + (&vv.x)[k];
  }
  *(float4*)(out + idx) = o;
}

extern "C" void kernel_launch(void* const* d_in, const int* in_sizes, int n_in,
                              void* d_out, int out_size, void* d_ws, size_t ws_size,
                              hipStream_t stream)
{
  (void)in_sizes; (void)n_in; (void)out_size; (void)ws_size;
  const float* v    = (const float*)d_in[0];
  const float* g_w  = (const float*)d_in[1];
  const float* g_b  = (const float*)d_in[2];
  const float* th_w = (const float*)d_in[3];
  const float* th_b = (const float*)d_in[4];
  const float* ph_w = (const float*)d_in[5];
  const float* ph_b = (const float*)d_in[6];
  const float* W_w  = (const float*)d_in[7];
  // d_in[8] = W_b: per-channel constant, exactly cancelled by BatchNorm mean. Unused.
  const float* gamma = (const float*)d_in[9];
  const float* beta  = (const float*)d_in[10];
  float* out = (float*)d_out;

  char* ws = (char*)d_ws;
  bf16* vbf  = (bf16*)ws;              // 64 MiB; dead after k_proj
  bf16* Wy   = (bf16*)ws;              // aliases vbf (written by k_wy, after k_mconv reads Mp)
  float* Mp  = (float*)ws;             // 16 MiB kc-partials; aliases dead vbf
  ws += (size_t)32768 * 1024 * 2;
  bf16* theta = (bf16*)ws;  ws += (size_t)32768 * 256 * 2;    // 16 MiB
  bf16* phiT  = (bf16*)ws;  ws += (size_t)32768 * 256 * 2;    // 16 MiB
  bf16* gT    = (bf16*)ws;  ws += (size_t)32768 * 256 * 2;    // 16 MiB
  bf16* Mbf   = (bf16*)ws;  ws += (size_t)8 * 65536 * 2;      // 1 MiB
  bf16* PT    = (bf16*)ws;  ws += (size_t)8 * 1024 * 256 * 2; // 4 MiB
  bf16* thwb  = (bf16*)ws;  ws += (size_t)256 * 1024 * 2;
  bf16* phwb  = (bf16*)ws;  ws += (size_t)256 * 1024 * 2;
  bf16* gwb   = (bf16*)ws;  ws += (size_t)256 * 1024 * 2;
  bf16* Wwb   = (bf16*)ws;  ws += (size_t)1024 * 256 * 2;
  float* sums = (float*)ws; ws += 4096;
  float* sumsq= (float*)ws; ws += 4096;

  k_cast_all<<<16384 + 512 + 1, 256, 0, stream>>>(v, vbf, th_w, ph_w, g_w, W_w,
                                                  thwb, phwb, gwb, Wwb, sums);

  k_proj <<<dim3(128, 6), 512, 0, stream>>>(vbf, thwb, th_b, phwb, ph_b, gwb, g_b, theta, phiT, gT);
  k_affin<<<dim3(8, 4, 8), 256, 0, stream>>>(phiT, gT, Mp);
  k_mconv<<<512, 256, 0, stream>>>(Mp, Mbf);
  k_pt   <<<dim3(8, 2, 8), 256, 0, stream>>>(Wwb, Mbf, PT);
  k_wy   <<<dim3(128, 8), 512, 0, stream>>>(theta, PT, Wy, sums, sumsq);
  k_out  <<<32768, 256, 0, stream>>>(Wy, v, sums, sumsq, gamma, beta, out);
}